// Round 4
// baseline (3132.071 us; speedup 1.0000x reference)
//
#include <hip/hip_runtime.h>
#include <math.h>

#define NG 76800
#define EG 307200
#define NL 38400
#define EL 153600
#define NB 64
#define NH 8

// ---------------- helpers ----------------
__device__ __forceinline__ unsigned enc_f(float x) {
    int i = __float_as_int(x);
    return (i >= 0) ? ((unsigned)i | 0x80000000u) : (unsigned)(~i);
}
__device__ __forceinline__ float dec_f(unsigned u) {
    int i = (u & 0x80000000u) ? (int)(u & 0x7FFFFFFFu) : (~(int)u);
    return __int_as_float(i);
}
__device__ __forceinline__ float sigmoidf(float x) { return 1.f / (1.f + expf(-x)); }

// ---------------- fp32 GEMM: C[M,Nsub] = A[M,K] @ W[K, :Nsub] (+bias) ----------------
// Optional Aadd: A-element (row m, col k) gets + Aadd[((e0+m)>>1)*K + k]
// (fuses the repeat(y2n,2) edge-feature add). W pre-offset by column; ldw = row stride.
__global__ __launch_bounds__(256) void gemm_kernel(const float* __restrict__ A,
                                                   const float* __restrict__ Aadd, int e0,
                                                   const float* __restrict__ W, int ldw,
                                                   const float* __restrict__ bias,
                                                   float* __restrict__ C,
                                                   int M, int K, int Nsub) {
    __shared__ float At[96][68];
    __shared__ float Ws[96][64];
    const int m0 = blockIdx.x * 64;
    const int n0 = blockIdx.y * 64;
    const int tid = threadIdx.x;

    for (int idx = tid; idx < 64 * K; idx += 256) {
        int r = idx / K;
        int k = idx - r * K;
        float a = A[(size_t)(m0 + r) * K + k];
        if (Aadd) a += Aadd[(size_t)((e0 + m0 + r) >> 1) * K + k];
        At[k][r] = a;
    }
    for (int idx = tid; idx < K * 64; idx += 256) {
        int k = idx >> 6;
        int c = idx & 63;
        int col = n0 + c;
        Ws[k][c] = (col < Nsub) ? W[(size_t)k * ldw + col] : 0.f;
    }
    __syncthreads();

    const int tx = tid & 15, ty = tid >> 4;
    float acc[4][4] = {};
    for (int k = 0; k < K; ++k) {
        float4 a4 = *(const float4*)&At[k][ty * 4];
        float4 w4 = *(const float4*)&Ws[k][tx * 4];
        float av[4] = {a4.x, a4.y, a4.z, a4.w};
        float wv[4] = {w4.x, w4.y, w4.z, w4.w};
#pragma unroll
        for (int i = 0; i < 4; ++i)
#pragma unroll
            for (int j = 0; j < 4; ++j) acc[i][j] += av[i] * wv[j];
    }
#pragma unroll
    for (int i = 0; i < 4; ++i) {
        int row = m0 + ty * 4 + i;
#pragma unroll
        for (int j = 0; j < 4; ++j) {
            int col = n0 + tx * 4 + j;
            if (col < Nsub) {
                float v = acc[i][j];
                if (bias) v += bias[col];
                C[(size_t)row * Nsub + col] = v;
            }
        }
    }
}

// ---------------- edge combine: wave-per-edge, pure streaming ----------------
// f_edge[c] = Pe[e,c] + Pni[src,c] + Pnj[dst,c]  (bias folded into Pni GEMM)
// leaky_relu -> esc[e,h] = sum_f v*attn ; fsum[e,:] += sum_h v (head-summed f_out)
// Lane layout: L=64/GH lanes per head; lane lam handles cnt consecutive cols.
template <int FE, bool WRITE_FSUM>
__global__ __launch_bounds__(256) void edge_combine_kernel(
    const int* __restrict__ src, const int* __restrict__ dst,
    const float* __restrict__ Pni,   // [N, GH*FE]
    const float* __restrict__ Pnj,   // [N, GH*FE]
    const float* __restrict__ Pe,    // [CH, GH*FE] (chunk-local)
    int GH,
    const float* __restrict__ attn,  // group-offset; indexed by c in [0, GH*FE)
    float* __restrict__ esc,         // [E, GH]
    float* __restrict__ fsum,        // [fsumE, FE] accumulated (+=)
    int e0, int CH, int fsumE) {
    const int wid = threadIdx.x >> 6;
    const int lane = threadIdx.x & 63;
    const int idx = blockIdx.x * 4 + wid;
    if (idx >= CH) return;
    const int e = e0 + idx;
    const int L = 64 / GH;
    const int h = lane / L;
    const int lam = lane - h * L;
    const int q = FE / L, rr = FE - q * L;
    const int cnt = (lam < rr) ? q + 1 : q;
    const int f0 = lam * q + (lam < rr ? lam : rr);
    const int cbase = h * FE + f0;
    const int cols = GH * FE;

    const float* pi = Pni + (size_t)src[e] * cols;
    const float* pj = Pnj + (size_t)dst[e] * cols;
    const float* pe = Pe + (size_t)idx * cols;

    float vj[5];
    float eh = 0.f;
#pragma unroll
    for (int j = 0; j < 5; ++j) {
        vj[j] = 0.f;
        if (j < cnt) {
            const int c = cbase + j;
            float v = pe[c] + pi[c] + pj[c];
            v = v > 0.f ? v : 0.01f * v;   // leaky_relu(0.01)
            eh += v * attn[c];
            vj[j] = v;
        }
    }
    for (int m = 1; m < L; m <<= 1) eh += __shfl_xor(eh, m, 64);
    if (lam == 0) esc[(size_t)e * GH + h] = eh;
    if (WRITE_FSUM && e < fsumE) {
#pragma unroll
        for (int j = 0; j < 5; ++j) {
            float vs = vj[j];
            for (int m = L; m < 64; m <<= 1) vs += __shfl_xor(vs, m, 64);
            if (h == 0 && j < cnt) fsum[(size_t)e * FE + f0 + j] += vs;
        }
    }
}

// ---------------- edge softmax (per head-group) ----------------
__global__ __launch_bounds__(256) void seg_max_kernel(const float* __restrict__ esc,
                                                      const int* __restrict__ dst,
                                                      unsigned* __restrict__ maxEnc,
                                                      int E, int ghShift) {
    int i = blockIdx.x * 256 + threadIdx.x;
    if (i >= (E << ghShift)) return;
    int e = i >> ghShift, h = i & ((1 << ghShift) - 1);
    atomicMax(&maxEnc[((size_t)dst[e] << ghShift) + h], enc_f(esc[i]));
}

__global__ __launch_bounds__(256) void seg_exp_kernel(float* __restrict__ esc,
                                                      const int* __restrict__ dst,
                                                      const unsigned* __restrict__ maxEnc,
                                                      float* __restrict__ denom,
                                                      int E, int ghShift) {
    int i = blockIdx.x * 256 + threadIdx.x;
    if (i >= (E << ghShift)) return;
    int e = i >> ghShift, h = i & ((1 << ghShift) - 1);
    float m = dec_f(maxEnc[((size_t)dst[e] << ghShift) + h]);
    float ex = expf(esc[i] - m);
    esc[i] = ex;
    atomicAdd(&denom[((size_t)dst[e] << ghShift) + h], ex);
}

// ---------------- aggregation: out[d,f] += sum_h a_h * Pnode[s, h, f] ----------------
__global__ __launch_bounds__(256) void agg_kernel(const int* __restrict__ src,
                                                  const int* __restrict__ dst,
                                                  const float* __restrict__ ex,     // [E,GH]
                                                  const float* __restrict__ denom,  // [N,GH]
                                                  const float* __restrict__ Pnode,  // [N, GH*Fn]
                                                  float* __restrict__ outp,         // [N, Fn] zeroed
                                                  int E, int Fn, int GH) {
    const int wid = threadIdx.x >> 6;
    const int lane = threadIdx.x & 63;
    const int e = blockIdx.x * 4 + wid;
    if (e >= E) return;
    const int s = src[e], d = dst[e];
    float a[NH];
    for (int h = 0; h < GH; ++h)
        a[h] = ex[(size_t)e * GH + h] / denom[(size_t)d * GH + h];
    const float* pr = Pnode + (size_t)s * GH * Fn;
    for (int f = lane; f < Fn; f += 64) {
        float v = 0.f;
        for (int h = 0; h < GH; ++h) v += a[h] * pr[h * Fn + f];
        atomicAdd(&outp[(size_t)d * Fn + f], v);
    }
}

// ---------------- readout ----------------
__global__ __launch_bounds__(256) void readout_kernel(const float* __restrict__ nfb,   // [NL,92]
                                                      const float* __restrict__ y22p,  // [NG,36]
                                                      const float* __restrict__ Wr1,   // [128,128]
                                                      const float* __restrict__ br1,
                                                      const float* __restrict__ Wr2,   // [128]
                                                      const float* __restrict__ br2,
                                                      float* __restrict__ out) {
    const int b = blockIdx.x;
    const int t = threadIdx.x;
    __shared__ float y[128];
    __shared__ float hh[128];
    __shared__ float red[128];
    if (t < 92) {
        float s = 0.f;
        const float* base = nfb + (size_t)b * 600 * 92 + t;
        for (int i = 0; i < 600; ++i) s += base[(size_t)i * 92];
        y[t] = s * (1.f / 600.f);
    } else if (t >= 128 && t < 164) {
        int f = t - 128;
        float s = 0.f;
        const float* base = y22p + (size_t)b * 1200 * 36 + f;
        for (int i = 0; i < 1200; ++i) s += base[(size_t)i * 36];
        y[92 + f] = s * (1.f / 1200.f);
    }
    __syncthreads();
    if (t < 128) {
        float s = br1[t];
        for (int c = 0; c < 128; ++c) s += y[c] * Wr1[(size_t)c * 128 + t];
        hh[t] = sigmoidf(s);
    }
    __syncthreads();
    if (t < 128) red[t] = hh[t] * Wr2[t];
    __syncthreads();
    for (int k = 64; k > 0; k >>= 1) {
        if (t < k) red[t] += red[t + k];
        __syncthreads();
    }
    if (t == 0) out[b] = sigmoidf(red[0] + br2[0]);
}

// ---------------- host side ----------------
static inline int cdiv(int a, int b) { return (a + b - 1) / b; }

extern "C" void kernel_launch(void* const* d_in, const int* in_sizes, int n_in,
                              void* d_out, int out_size, void* d_ws, size_t ws_size,
                              hipStream_t stream) {
    const int* gg_src = (const int*)d_in[0];
    const int* gg_dst = (const int*)d_in[1];
    const float* gg_nf = (const float*)d_in[2];
    const float* gg_ef = (const float*)d_in[3];
    const int* lg_src = (const int*)d_in[4];
    const int* lg_dst = (const int*)d_in[5];
    const float* lg_nf = (const float*)d_in[6];
    const float* lg_ef = (const float*)d_in[7];
    const float* W_node1 = (const float*)d_in[8];
    const float* b_node1 = (const float*)d_in[9];
    const float* W_ni1 = (const float*)d_in[10];
    const float* W_nj1 = (const float*)d_in[11];
    const float* W_fij1 = (const float*)d_in[12];
    const float* attn1 = (const float*)d_in[13];
    const float* bias1 = (const float*)d_in[14];
    const float* W_node2a = (const float*)d_in[15];
    const float* b_node2a = (const float*)d_in[16];
    const float* W_ni2a = (const float*)d_in[17];
    const float* W_nj2a = (const float*)d_in[18];
    const float* W_fij2a = (const float*)d_in[19];
    const float* attn2a = (const float*)d_in[20];
    const float* bias2a = (const float*)d_in[21];
    const float* W_node2b = (const float*)d_in[22];
    const float* b_node2b = (const float*)d_in[23];
    const float* W_ni2b = (const float*)d_in[24];
    const float* W_nj2b = (const float*)d_in[25];
    const float* W_fij2b = (const float*)d_in[26];
    const float* attn2b = (const float*)d_in[27];
    const float* bias2b = (const float*)d_in[28];
    const float* Wr1 = (const float*)d_in[29];
    const float* br1 = (const float*)d_in[30];
    const float* Wr2 = (const float*)d_in[31];
    const float* br2 = (const float*)d_in[32];
    float* out = (float*)d_out;

    // Layout matches round-3 footprint (~268 MB, known to fit).
    char* ws = (char*)d_ws;
    size_t off = 0;
    auto take = [&](size_t bytes) {
        size_t o = off;
        off += (bytes + 255) & ~(size_t)255;
        return (void*)(ws + o);
    };
    float* y2n = (float*)take((size_t)NG * 40 * 4);
    float* y22p = (float*)take((size_t)NG * 36 * 4);
    float* nfa = (float*)take((size_t)NL * 92 * 4);
    float* efa = (float*)take((size_t)EL * 40 * 4);
    float* nfb = (float*)take((size_t)NL * 92 * 4);
    float* esc = (float*)take((size_t)EG * NH * 4);
    unsigned* maxE = (unsigned*)take((size_t)NG * NH * 4);
    float* den = (float*)take((size_t)NG * NH * 4);
    float* slab = (float*)take(2 * (size_t)NG * NH * 36 * 4);   // 44.24M floats

    auto gemm = [&](const float* A, const float* Aadd, int e0, const float* W, int ldw,
                    const float* bias, float* C, int M, int K, int Nsub) {
        dim3 grid(M / 64, cdiv(Nsub, 64));
        gemm_kernel<<<grid, 256, 0, stream>>>(A, Aadd, e0, W, ldw, bias, C, M, K, Nsub);
    };

    // ---------------- stage 1 (gg), 2 passes of GH1=4 heads ----------------
    hipMemsetAsync(y2n, 0, (size_t)NG * 40 * 4, stream);
    hipMemsetAsync(y22p, 0, (size_t)NG * 36 * 4, stream);
    for (int g = 0; g < 2; ++g) {
        const int c0 = g * 144;     // 4 heads * FE=36
        const int c0n = g * 160;    // 4 heads * Fn=40
        hipMemsetAsync(maxE, 0, (size_t)NG * 4 * 4, stream);
        hipMemsetAsync(den, 0, (size_t)NG * 4 * 4, stream);
        float* Pni = slab;                               // NG*144
        float* Pnj = slab + (size_t)NG * 144;            // NG*144
        float* Pe = slab + 2 * (size_t)NG * 144;         // 153600*144 (chunk)
        gemm(gg_nf, nullptr, 0, W_ni1 + c0, 288, bias1 + c0, Pni, NG, 40, 144);
        gemm(gg_nf, nullptr, 0, W_nj1 + c0, 288, nullptr, Pnj, NG, 40, 144);
        for (int ch = 0; ch < 2; ++ch) {
            const int e0 = ch * 153600;
            gemm(gg_ef + (size_t)e0 * 10, nullptr, 0, W_fij1 + c0, 288, nullptr,
                 Pe, 153600, 10, 144);
            edge_combine_kernel<36, true><<<153600 / 4, 256, 0, stream>>>(
                gg_src, gg_dst, Pni, Pnj, Pe, 4, attn1 + c0, esc, y22p, e0, 153600, NG);
        }
        seg_max_kernel<<<cdiv(EG * 4, 256), 256, 0, stream>>>(esc, gg_dst, maxE, EG, 2);
        seg_exp_kernel<<<cdiv(EG * 4, 256), 256, 0, stream>>>(esc, gg_dst, maxE, den, EG, 2);
        float* Pnode = slab;   // alias: Pni/Pnj/Pe dead
        gemm(gg_nf, nullptr, 0, W_node1 + c0n, 320, b_node1 + c0n, Pnode, NG, 40, 160);
        agg_kernel<<<cdiv(EG, 4), 256, 0, stream>>>(gg_src, gg_dst, esc, den, Pnode, y2n, EG, 40, 4);
    }

    // ---------------- stage 2 (lg), GH=8, two layers ----------------
    hipMemsetAsync(nfa, 0, (size_t)NL * 92 * 4, stream);
    hipMemsetAsync(efa, 0, (size_t)EL * 40 * 4, stream);
    for (int layer = 0; layer < 2; ++layer) {
        const bool a = (layer == 0);
        const float* nf_in = a ? lg_nf : nfa;
        const float* ef_in = a ? lg_ef : efa;
        const float* Wni = a ? W_ni2a : W_ni2b;
        const float* Wnj = a ? W_nj2a : W_nj2b;
        const float* Wfij = a ? W_fij2a : W_fij2b;
        const float* Wnode = a ? W_node2a : W_node2b;
        const float* bn = a ? b_node2a : b_node2b;
        const float* bs = a ? bias2a : bias2b;
        const float* at = a ? attn2a : attn2b;
        float* nf_out = a ? nfa : nfb;

        hipMemsetAsync(maxE, 0, (size_t)NL * 8 * 4, stream);
        hipMemsetAsync(den, 0, (size_t)NL * 8 * 4, stream);
        hipMemsetAsync(nf_out, 0, (size_t)NL * 92 * 4, stream);
        float* Pni = slab;                                // NL*320 = 12.29M
        float* Pnj = slab + (size_t)NL * 320;
        float* Pe = slab + 2 * (size_t)NL * 320;          // 38400*320 chunk
        gemm(nf_in, nullptr, 0, Wni, 320, bs, Pni, NL, 92, 320);
        gemm(nf_in, nullptr, 0, Wnj, 320, nullptr, Pnj, NL, 92, 320);
        for (int ch = 0; ch < 4; ++ch) {
            const int e0 = ch * 38400;
            gemm(ef_in + (size_t)e0 * 40, a ? y2n : nullptr, e0, Wfij, 320, nullptr,
                 Pe, 38400, 40, 320);
            if (a)
                edge_combine_kernel<40, true><<<38400 / 4, 256, 0, stream>>>(
                    lg_src, lg_dst, Pni, Pnj, Pe, 8, at, esc, efa, e0, 38400, EL);
            else
                edge_combine_kernel<40, false><<<38400 / 4, 256, 0, stream>>>(
                    lg_src, lg_dst, Pni, Pnj, Pe, 8, at, esc, nullptr, e0, 38400, 0);
        }
        seg_max_kernel<<<cdiv(EL * 8, 256), 256, 0, stream>>>(esc, lg_dst, maxE, EL, 3);
        seg_exp_kernel<<<cdiv(EL * 8, 256), 256, 0, stream>>>(esc, lg_dst, maxE, den, EL, 3);
        float* Pnode = slab;   // alias: Pni/Pnj/Pe dead
        gemm(nf_in, nullptr, 0, Wnode, 736, bn, Pnode, NL, 92, 736);
        agg_kernel<<<cdiv(EL, 4), 256, 0, stream>>>(lg_src, lg_dst, esc, den, Pnode, nf_out, EL, 92, 8);
    }

    // ---------------- readout ----------------
    readout_kernel<<<NB, 256, 0, stream>>>(nfb, y22p, Wr1, br1, Wr2, br2, out);
}

// Round 5
// 2976.195 us; speedup vs baseline: 1.0524x; 1.0524x over previous
//
#include <hip/hip_runtime.h>
#include <math.h>

#define NG 76800
#define EG 307200
#define NL 38400
#define EL 153600
#define NB 64
#define NH 8

typedef __attribute__((ext_vector_type(8))) short bf16x8;
typedef __attribute__((ext_vector_type(4))) float f32x4;

__device__ __forceinline__ float sigmoidf(float x) { return 1.f / (1.f + expf(-x)); }
__device__ __forceinline__ unsigned short f2bf(float x) {
    unsigned u = __float_as_uint(x);
    return (unsigned short)((u + 0x7FFFu + ((u >> 16) & 1u)) >> 16);
}

// ---------------- bf16 MFMA GEMM: C[M,Nsub] = A[M,K] @ W[K,:Nsub] (+bias) ----------------
// fp32 in/out; A,W rounded to bf16 during LDS staging; fp32 MFMA accumulate.
// 64x64 tile, K<=96 in one shot (padded to mult of 32). M % 64 == 0.
// Optional Aadd: A(row m,col k) += Aadd[((e0+m)>>1)*K+k]  (repeat(y2n,2) fusion).
__global__ __launch_bounds__(256) void gemm_kernel(const float* __restrict__ A,
                                                   const float* __restrict__ Aadd, int e0,
                                                   const float* __restrict__ W, int ldw,
                                                   const float* __restrict__ bias,
                                                   float* __restrict__ C,
                                                   int M, int K, int Nsub) {
    __shared__ unsigned short As[64][104];   // [m][k], stride 104 (2-way bank alias: free)
    __shared__ unsigned short Bs[64][104];   // [n][k]
    const int m0 = blockIdx.x * 64;
    const int n0 = blockIdx.y * 64;
    const int tid = threadIdx.x;
    const int Kpad = (K + 31) & ~31;

    for (int idx = tid; idx < 64 * Kpad; idx += 256) {
        int r = idx / Kpad;
        int k = idx - r * Kpad;
        float a = 0.f;
        if (k < K) {
            a = A[(size_t)(m0 + r) * K + k];
            if (Aadd) a += Aadd[(size_t)((e0 + m0 + r) >> 1) * K + k];
        }
        As[r][k] = f2bf(a);
    }
    for (int idx = tid; idx < (Kpad << 6); idx += 256) {
        int k = idx >> 6;
        int n = idx & 63;
        int col = n0 + n;
        float w = (k < K && col < Nsub) ? W[(size_t)k * ldw + col] : 0.f;
        Bs[n][k] = f2bf(w);
    }
    __syncthreads();

    const int wv = tid >> 6;
    const int lane = tid & 63;
    const int q = lane >> 4;
    const int mrow = lane & 15;

    f32x4 acc[4];
#pragma unroll
    for (int t = 0; t < 4; ++t) acc[t] = (f32x4){0.f, 0.f, 0.f, 0.f};

    for (int k0 = 0; k0 < Kpad; k0 += 32) {
        bf16x8 af = *(const bf16x8*)&As[wv * 16 + mrow][k0 + q * 8];
#pragma unroll
        for (int t = 0; t < 4; ++t) {
            bf16x8 bf = *(const bf16x8*)&Bs[t * 16 + mrow][k0 + q * 8];
            acc[t] = __builtin_amdgcn_mfma_f32_16x16x32_bf16(af, bf, acc[t], 0, 0, 0);
        }
    }

#pragma unroll
    for (int t = 0; t < 4; ++t) {
        int col = n0 + t * 16 + mrow;
        if (col < Nsub) {
            float b = bias ? bias[col] : 0.f;
#pragma unroll
            for (int r = 0; r < 4; ++r) {
                int row = m0 + wv * 16 + q * 4 + r;
                C[(size_t)row * Nsub + col] = acc[t][r] + b;
            }
        }
    }
}

// ---------------- edge combine: wave-per-edge, pure streaming ----------------
template <int FE, bool WRITE_FSUM>
__global__ __launch_bounds__(256) void edge_combine_kernel(
    const int* __restrict__ src, const int* __restrict__ dst,
    const float* __restrict__ Pni,   // [N, GH*FE]
    const float* __restrict__ Pnj,   // [N, GH*FE]
    const float* __restrict__ Pe,    // [CH, GH*FE] (chunk-local)
    int GH,
    const float* __restrict__ attn,  // group-offset
    float* __restrict__ esc,         // [E, GH]
    float* __restrict__ fsum,        // [fsumE, FE]
    int e0, int CH, int fsumE, int accum) {
    const int wid = threadIdx.x >> 6;
    const int lane = threadIdx.x & 63;
    const int idx = blockIdx.x * 4 + wid;
    if (idx >= CH) return;
    const int e = e0 + idx;
    const int L = 64 / GH;
    const int h = lane / L;
    const int lam = lane - h * L;
    const int q = FE / L, rr = FE - q * L;
    const int cnt = (lam < rr) ? q + 1 : q;
    const int f0 = lam * q + (lam < rr ? lam : rr);
    const int cbase = h * FE + f0;
    const int cols = GH * FE;

    const float* pi = Pni + (size_t)src[e] * cols;
    const float* pj = Pnj + (size_t)dst[e] * cols;
    const float* pe = Pe + (size_t)idx * cols;

    float vj[5];
    float eh = 0.f;
#pragma unroll
    for (int j = 0; j < 5; ++j) {
        vj[j] = 0.f;
        if (j < cnt) {
            const int c = cbase + j;
            float v = pe[c] + pi[c] + pj[c];
            v = v > 0.f ? v : 0.01f * v;   // leaky_relu(0.01)
            eh += v * attn[c];
            vj[j] = v;
        }
    }
    for (int m = 1; m < L; m <<= 1) eh += __shfl_xor(eh, m, 64);
    if (lam == 0) esc[(size_t)e * GH + h] = eh;
    if (WRITE_FSUM && e < fsumE) {
#pragma unroll
        for (int j = 0; j < 5; ++j) {
            float vs = vj[j];
            for (int m = L; m < 64; m <<= 1) vs += __shfl_xor(vs, m, 64);
            if (h == 0 && j < cnt) {
                float* p = &fsum[(size_t)e * FE + f0 + j];
                *p = accum ? (*p + vs) : vs;
            }
        }
    }
}

// ---------------- CSR build ----------------
__global__ __launch_bounds__(256) void hist_kernel(const int* __restrict__ dst,
                                                   int* __restrict__ cnt, int E) {
    int i = blockIdx.x * 256 + threadIdx.x;
    if (i < E) atomicAdd(&cnt[dst[i]], 1);
}

__global__ __launch_bounds__(1024) void scan_block_kernel(const int* __restrict__ cnt,
                                                          int* __restrict__ excl,
                                                          int* __restrict__ bsum, int N) {
    __shared__ int sd[1024];
    const int tid = threadIdx.x;
    const int i = blockIdx.x * 1024 + tid;
    int v = (i < N) ? cnt[i] : 0;
    sd[tid] = v;
    __syncthreads();
    for (int off = 1; off < 1024; off <<= 1) {
        int t = (tid >= off) ? sd[tid - off] : 0;
        __syncthreads();
        sd[tid] += t;
        __syncthreads();
    }
    if (i < N) excl[i] = sd[tid] - v;
    if (tid == 1023) bsum[blockIdx.x] = sd[1023];
}

__global__ void scan_top_kernel(int* __restrict__ bsum, int nblk) {
    if (threadIdx.x == 0 && blockIdx.x == 0) {
        int run = 0;
        for (int b = 0; b < nblk; ++b) {
            int t = bsum[b];
            bsum[b] = run;
            run += t;
        }
    }
}

__global__ __launch_bounds__(256) void scan_add_kernel(int* __restrict__ row_ptr,
                                                       const int* __restrict__ bsum,
                                                       int N, int E) {
    int i = blockIdx.x * 256 + threadIdx.x;
    if (i < N) row_ptr[i] += bsum[i >> 10];
    if (i == 0) row_ptr[N] = E;
}

__global__ __launch_bounds__(256) void scatter_kernel(const int* __restrict__ dst,
                                                      const int* __restrict__ row_ptr,
                                                      int* __restrict__ cur,
                                                      int* __restrict__ eidx, int E) {
    int i = blockIdx.x * 256 + threadIdx.x;
    if (i < E) {
        int d = dst[i];
        int pos = atomicAdd(&cur[d], 1);
        eidx[row_ptr[d] + pos] = i;
    }
}

// ---------------- node softmax + aggregation (CSR, wave-per-node) ----------------
// out[d,f] = sum_{e in in(d)} sum_h softmax_h(e) * Pnode[src_e, h*Fn+f]
template <int Fn>
__global__ __launch_bounds__(256) void node_agg_kernel(
    const int* __restrict__ row_ptr, const int* __restrict__ eidx,
    const int* __restrict__ src,
    const float* __restrict__ esc,    // [E, GH]
    const float* __restrict__ Pnode,  // [N, GH*Fn]
    float* __restrict__ outp,         // [N, Fn]
    int N, int GH, int accum) {
    const int wid = threadIdx.x >> 6;
    const int lane = threadIdx.x & 63;
    const int nid = blockIdx.x * 4 + wid;
    if (nid >= N) return;
    const int r0 = row_ptr[nid], r1 = row_ptr[nid + 1];

    float m[NH], den[NH];
    for (int h = 0; h < GH; ++h) { m[h] = -1e30f; den[h] = 0.f; }
    for (int i = r0; i < r1; ++i) {
        const float* ep = esc + (size_t)eidx[i] * GH;
        for (int h = 0; h < GH; ++h) m[h] = fmaxf(m[h], ep[h]);
    }
    for (int i = r0; i < r1; ++i) {
        const float* ep = esc + (size_t)eidx[i] * GH;
        for (int h = 0; h < GH; ++h) den[h] += expf(ep[h] - m[h]);
    }
    for (int h = 0; h < GH; ++h) den[h] = 1.f / den[h];

    const int c0 = lane, c1 = lane + 64;
    float acc0 = 0.f, acc1 = 0.f;
    for (int i = r0; i < r1; ++i) {
        const int e = eidx[i];
        const float* ep = esc + (size_t)e * GH;
        const float* pr = Pnode + (size_t)src[e] * GH * Fn;
        for (int h = 0; h < GH; ++h) {
            float w = expf(ep[h] - m[h]) * den[h];
            if (c0 < Fn) acc0 += w * pr[h * Fn + c0];
            if (Fn > 64 && c1 < Fn) acc1 += w * pr[h * Fn + c1];
        }
    }
    if (c0 < Fn) {
        float* p = &outp[(size_t)nid * Fn + c0];
        *p = accum ? (*p + acc0) : acc0;
    }
    if (Fn > 64 && c1 < Fn) {
        float* p = &outp[(size_t)nid * Fn + c1];
        *p = accum ? (*p + acc1) : acc1;
    }
}

// ---------------- readout ----------------
__global__ __launch_bounds__(256) void readout_kernel(const float* __restrict__ nfb,
                                                      const float* __restrict__ y22p,
                                                      const float* __restrict__ Wr1,
                                                      const float* __restrict__ br1,
                                                      const float* __restrict__ Wr2,
                                                      const float* __restrict__ br2,
                                                      float* __restrict__ out) {
    const int b = blockIdx.x;
    const int t = threadIdx.x;
    __shared__ float y[128];
    __shared__ float hh[128];
    __shared__ float red[128];
    if (t < 92) {
        float s = 0.f;
        const float* base = nfb + (size_t)b * 600 * 92 + t;
        for (int i = 0; i < 600; ++i) s += base[(size_t)i * 92];
        y[t] = s * (1.f / 600.f);
    } else if (t >= 128 && t < 164) {
        int f = t - 128;
        float s = 0.f;
        const float* base = y22p + (size_t)b * 1200 * 36 + f;
        for (int i = 0; i < 1200; ++i) s += base[(size_t)i * 36];
        y[92 + f] = s * (1.f / 1200.f);
    }
    __syncthreads();
    if (t < 128) {
        float s = br1[t];
        for (int c = 0; c < 128; ++c) s += y[c] * Wr1[(size_t)c * 128 + t];
        hh[t] = sigmoidf(s);
    }
    __syncthreads();
    if (t < 128) red[t] = hh[t] * Wr2[t];
    __syncthreads();
    for (int k = 64; k > 0; k >>= 1) {
        if (t < k) red[t] += red[t + k];
        __syncthreads();
    }
    if (t == 0) out[b] = sigmoidf(red[0] + br2[0]);
}

// ---------------- host side ----------------
static inline int cdiv(int a, int b) { return (a + b - 1) / b; }

extern "C" void kernel_launch(void* const* d_in, const int* in_sizes, int n_in,
                              void* d_out, int out_size, void* d_ws, size_t ws_size,
                              hipStream_t stream) {
    const int* gg_src = (const int*)d_in[0];
    const int* gg_dst = (const int*)d_in[1];
    const float* gg_nf = (const float*)d_in[2];
    const float* gg_ef = (const float*)d_in[3];
    const int* lg_src = (const int*)d_in[4];
    const int* lg_dst = (const int*)d_in[5];
    const float* lg_nf = (const float*)d_in[6];
    const float* lg_ef = (const float*)d_in[7];
    const float* W_node1 = (const float*)d_in[8];
    const float* b_node1 = (const float*)d_in[9];
    const float* W_ni1 = (const float*)d_in[10];
    const float* W_nj1 = (const float*)d_in[11];
    const float* W_fij1 = (const float*)d_in[12];
    const float* attn1 = (const float*)d_in[13];
    const float* bias1 = (const float*)d_in[14];
    const float* W_node2a = (const float*)d_in[15];
    const float* b_node2a = (const float*)d_in[16];
    const float* W_ni2a = (const float*)d_in[17];
    const float* W_nj2a = (const float*)d_in[18];
    const float* W_fij2a = (const float*)d_in[19];
    const float* attn2a = (const float*)d_in[20];
    const float* bias2a = (const float*)d_in[21];
    const float* W_node2b = (const float*)d_in[22];
    const float* b_node2b = (const float*)d_in[23];
    const float* W_ni2b = (const float*)d_in[24];
    const float* W_nj2b = (const float*)d_in[25];
    const float* W_fij2b = (const float*)d_in[26];
    const float* attn2b = (const float*)d_in[27];
    const float* bias2b = (const float*)d_in[28];
    const float* Wr1 = (const float*)d_in[29];
    const float* br1 = (const float*)d_in[30];
    const float* Wr2 = (const float*)d_in[31];
    const float* br2 = (const float*)d_in[32];
    float* out = (float*)d_out;

    char* ws = (char*)d_ws;
    size_t off = 0;
    auto take = [&](size_t bytes) {
        size_t o = off;
        off += (bytes + 255) & ~(size_t)255;
        return (void*)(ws + o);
    };
    float* y2n = (float*)take((size_t)NG * 40 * 4);
    float* y22p = (float*)take((size_t)NG * 36 * 4);
    float* nfa = (float*)take((size_t)NL * 92 * 4);
    float* efa = (float*)take((size_t)EL * 40 * 4);
    float* nfb = (float*)take((size_t)NL * 92 * 4);
    float* esc = (float*)take((size_t)EG * 4 * 4);        // EG*4 == EL*8
    int* gg_row = (int*)take((size_t)(NG + 1) * 4);
    int* gg_eidx = (int*)take((size_t)EG * 4);
    int* gg_cnt = (int*)take((size_t)NG * 4);
    int* lg_row = (int*)take((size_t)(NL + 1) * 4);
    int* lg_eidx = (int*)take((size_t)EL * 4);
    int* lg_cnt = (int*)take((size_t)NL * 4);
    int* bsum = (int*)take((size_t)128 * 4);
    float* slab = (float*)take(2 * (size_t)NG * 288 * 4);  // 176.9 MB

    auto gemm = [&](const float* A, const float* Aadd, int e0, const float* W, int ldw,
                    const float* bias, float* C, int M, int K, int Nsub) {
        dim3 grid(M / 64, cdiv(Nsub, 64));
        gemm_kernel<<<grid, 256, 0, stream>>>(A, Aadd, e0, W, ldw, bias, C, M, K, Nsub);
    };
    auto build_csr = [&](const int* dst, int* row_ptr, int* eidx, int* cnt, int N, int E) {
        hipMemsetAsync(cnt, 0, (size_t)N * 4, stream);
        hist_kernel<<<cdiv(E, 256), 256, 0, stream>>>(dst, cnt, E);
        int nblk = cdiv(N, 1024);
        scan_block_kernel<<<nblk, 1024, 0, stream>>>(cnt, row_ptr, bsum, N);
        scan_top_kernel<<<1, 64, 0, stream>>>(bsum, nblk);
        scan_add_kernel<<<cdiv(N, 256), 256, 0, stream>>>(row_ptr, bsum, N, E);
        hipMemsetAsync(cnt, 0, (size_t)N * 4, stream);
        scatter_kernel<<<cdiv(E, 256), 256, 0, stream>>>(dst, row_ptr, cnt, eidx, E);
    };

    build_csr(gg_dst, gg_row, gg_eidx, gg_cnt, NG, EG);
    build_csr(lg_dst, lg_row, lg_eidx, lg_cnt, NL, EL);

    // ---------------- stage 1 (gg), 2 groups of 4 heads ----------------
    for (int g = 0; g < 2; ++g) {
        const int c0 = g * 144;     // 4 heads * FE=36
        const int c0n = g * 160;    // 4 heads * Fn=40
        float* Pni = slab;                               // NG*144
        float* Pnj = slab + (size_t)NG * 144;
        float* Pe = slab + 2 * (size_t)NG * 144;         // 153600*144 chunk
        gemm(gg_nf, nullptr, 0, W_ni1 + c0, 288, bias1 + c0, Pni, NG, 40, 144);
        gemm(gg_nf, nullptr, 0, W_nj1 + c0, 288, nullptr, Pnj, NG, 40, 144);
        for (int ch = 0; ch < 2; ++ch) {
            const int e0 = ch * 153600;
            gemm(gg_ef + (size_t)e0 * 10, nullptr, 0, W_fij1 + c0, 288, nullptr,
                 Pe, 153600, 10, 144);
            edge_combine_kernel<36, true><<<153600 / 4, 256, 0, stream>>>(
                gg_src, gg_dst, Pni, Pnj, Pe, 4, attn1 + c0, esc, y22p, e0, 153600, NG, g);
        }
        float* Pnode = slab;   // alias: Pni/Pnj/Pe dead
        gemm(gg_nf, nullptr, 0, W_node1 + c0n, 320, b_node1 + c0n, Pnode, NG, 40, 160);
        node_agg_kernel<40><<<NG / 4, 256, 0, stream>>>(gg_row, gg_eidx, gg_src, esc,
                                                        Pnode, y2n, NG, 4, g);
    }

    // ---------------- stage 2 (lg), GH=8, two layers ----------------
    for (int layer = 0; layer < 2; ++layer) {
        const bool a = (layer == 0);
        const float* nf_in = a ? lg_nf : nfa;
        const float* ef_in = a ? lg_ef : efa;
        const float* Wni = a ? W_ni2a : W_ni2b;
        const float* Wnj = a ? W_nj2a : W_nj2b;
        const float* Wfij = a ? W_fij2a : W_fij2b;
        const float* Wnode = a ? W_node2a : W_node2b;
        const float* bn = a ? b_node2a : b_node2b;
        const float* bs = a ? bias2a : bias2b;
        const float* at = a ? attn2a : attn2b;
        float* nf_out = a ? nfa : nfb;

        float* Pni = slab;                                // NL*320
        float* Pnj = slab + (size_t)NL * 320;
        float* Pe = slab + 2 * (size_t)NL * 320;          // 38400*320 chunk
        gemm(nf_in, nullptr, 0, Wni, 320, bs, Pni, NL, 92, 320);
        gemm(nf_in, nullptr, 0, Wnj, 320, nullptr, Pnj, NL, 92, 320);
        for (int ch = 0; ch < 4; ++ch) {
            const int e0 = ch * 38400;
            gemm(ef_in + (size_t)e0 * 40, a ? y2n : nullptr, e0, Wfij, 320, nullptr,
                 Pe, 38400, 40, 320);
            if (a)
                edge_combine_kernel<40, true><<<38400 / 4, 256, 0, stream>>>(
                    lg_src, lg_dst, Pni, Pnj, Pe, 8, at, esc, efa, e0, 38400, EL, 0);
            else
                edge_combine_kernel<40, false><<<38400 / 4, 256, 0, stream>>>(
                    lg_src, lg_dst, Pni, Pnj, Pe, 8, at, esc, nullptr, e0, 38400, 0, 0);
        }
        float* Pnode = slab;   // alias: Pni/Pnj/Pe dead
        gemm(nf_in, nullptr, 0, Wnode, 736, bn, Pnode, NL, 92, 736);
        node_agg_kernel<92><<<NL / 4, 256, 0, stream>>>(lg_row, lg_eidx, lg_src, esc,
                                                        Pnode, nf_out, NL, 8, 0);
    }

    // ---------------- readout ----------------
    readout_kernel<<<NB, 256, 0, stream>>>(nfb, y22p, Wr1, br1, Wr2, br2, out);
}

// Round 6
// 2274.861 us; speedup vs baseline: 1.3768x; 1.3083x over previous
//
#include <hip/hip_runtime.h>
#include <math.h>

#define NG 76800
#define EG 307200
#define NL 38400
#define EL 153600
#define NB 64
#define NH 8

typedef __attribute__((ext_vector_type(8))) short bf16x8;
typedef __attribute__((ext_vector_type(4))) float f32x4;

__device__ __forceinline__ float sigmoidf(float x) { return 1.f / (1.f + expf(-x)); }
__device__ __forceinline__ unsigned short f2bf(float x) {
    unsigned u = __float_as_uint(x);
    return (unsigned short)((u + 0x7FFFu + ((u >> 16) & 1u)) >> 16);
}

// ---------------- bf16 MFMA GEMM: C[M,Nsub] = A[M,K] @ W[K,:Nsub] (+bias) ----------------
__global__ __launch_bounds__(256) void gemm_kernel(const float* __restrict__ A,
                                                   const float* __restrict__ Aadd, int e0,
                                                   const float* __restrict__ W, int ldw,
                                                   const float* __restrict__ bias,
                                                   float* __restrict__ C,
                                                   int M, int K, int Nsub) {
    __shared__ unsigned short As[64][104];
    __shared__ unsigned short Bs[64][104];
    const int m0 = blockIdx.x * 64;
    const int n0 = blockIdx.y * 64;
    const int tid = threadIdx.x;
    const int Kpad = (K + 31) & ~31;

    for (int idx = tid; idx < 64 * Kpad; idx += 256) {
        int r = idx / Kpad;
        int k = idx - r * Kpad;
        float a = 0.f;
        if (k < K) {
            a = A[(size_t)(m0 + r) * K + k];
            if (Aadd) a += Aadd[(size_t)((e0 + m0 + r) >> 1) * K + k];
        }
        As[r][k] = f2bf(a);
    }
    for (int idx = tid; idx < (Kpad << 6); idx += 256) {
        int k = idx >> 6;
        int n = idx & 63;
        int col = n0 + n;
        float w = (k < K && col < Nsub) ? W[(size_t)k * ldw + col] : 0.f;
        Bs[n][k] = f2bf(w);
    }
    __syncthreads();

    const int wv = tid >> 6;
    const int lane = tid & 63;
    const int q = lane >> 4;
    const int mrow = lane & 15;

    f32x4 acc[4];
#pragma unroll
    for (int t = 0; t < 4; ++t) acc[t] = (f32x4){0.f, 0.f, 0.f, 0.f};

    for (int k0 = 0; k0 < Kpad; k0 += 32) {
        bf16x8 af = *(const bf16x8*)&As[wv * 16 + mrow][k0 + q * 8];
#pragma unroll
        for (int t = 0; t < 4; ++t) {
            bf16x8 bf = *(const bf16x8*)&Bs[t * 16 + mrow][k0 + q * 8];
            acc[t] = __builtin_amdgcn_mfma_f32_16x16x32_bf16(af, bf, acc[t], 0, 0, 0);
        }
    }

#pragma unroll
    for (int t = 0; t < 4; ++t) {
        int col = n0 + t * 16 + mrow;
        if (col < Nsub) {
            float b = bias ? bias[col] : 0.f;
#pragma unroll
            for (int r = 0; r < 4; ++r) {
                int row = m0 + wv * 16 + q * 4 + r;
                C[(size_t)row * Nsub + col] = acc[t][r] + b;
            }
        }
    }
}

// ---------------- edge combine: wave-per-edge, pure streaming ----------------
template <int FE, bool WRITE_FSUM>
__global__ __launch_bounds__(256) void edge_combine_kernel(
    const int* __restrict__ src, const int* __restrict__ dst,
    const float* __restrict__ Pni,   // [N, GH*FE]
    const float* __restrict__ Pnj,   // [N, GH*FE]
    const float* __restrict__ Pe,    // [CH, GH*FE] (chunk-local)
    int GH,
    const float* __restrict__ attn,  // group-offset
    float* __restrict__ esc,         // [E, GH]
    float* __restrict__ fsum,        // [fsumE, FE]
    int e0, int CH, int fsumE, int accum) {
    const int wid = threadIdx.x >> 6;
    const int lane = threadIdx.x & 63;
    const int idx = blockIdx.x * 4 + wid;
    if (idx >= CH) return;
    const int e = e0 + idx;
    const int L = 64 / GH;
    const int h = lane / L;
    const int lam = lane - h * L;
    const int q = FE / L, rr = FE - q * L;
    const int cnt = (lam < rr) ? q + 1 : q;
    const int f0 = lam * q + (lam < rr ? lam : rr);
    const int cbase = h * FE + f0;
    const int cols = GH * FE;

    const float* pi = Pni + (size_t)src[e] * cols;
    const float* pj = Pnj + (size_t)dst[e] * cols;
    const float* pe = Pe + (size_t)idx * cols;

    float vj[5];
    float eh = 0.f;
#pragma unroll
    for (int j = 0; j < 5; ++j) {
        vj[j] = 0.f;
        if (j < cnt) {
            const int c = cbase + j;
            float v = pe[c] + pi[c] + pj[c];
            v = v > 0.f ? v : 0.01f * v;   // leaky_relu(0.01)
            eh += v * attn[c];
            vj[j] = v;
        }
    }
    for (int m = 1; m < L; m <<= 1) eh += __shfl_xor(eh, m, 64);
    if (lam == 0) esc[(size_t)e * GH + h] = eh;
    if (WRITE_FSUM && e < fsumE) {
#pragma unroll
        for (int j = 0; j < 5; ++j) {
            float vs = vj[j];
            for (int m = L; m < 64; m <<= 1) vs += __shfl_xor(vs, m, 64);
            if (h == 0 && j < cnt) {
                float* p = &fsum[(size_t)e * FE + f0 + j];
                *p = accum ? (*p + vs) : vs;
            }
        }
    }
}

// ---------------- CSR build ----------------
__global__ __launch_bounds__(256) void hist_kernel(const int* __restrict__ dst,
                                                   int* __restrict__ cnt, int E) {
    int i = blockIdx.x * 256 + threadIdx.x;
    if (i < E) atomicAdd(&cnt[dst[i]], 1);
}

__global__ __launch_bounds__(1024) void scan_block_kernel(const int* __restrict__ cnt,
                                                          int* __restrict__ excl,
                                                          int* __restrict__ bsum, int N) {
    __shared__ int sd[1024];
    const int tid = threadIdx.x;
    const int i = blockIdx.x * 1024 + tid;
    int v = (i < N) ? cnt[i] : 0;
    sd[tid] = v;
    __syncthreads();
    for (int off = 1; off < 1024; off <<= 1) {
        int t = (tid >= off) ? sd[tid - off] : 0;
        __syncthreads();
        sd[tid] += t;
        __syncthreads();
    }
    if (i < N) excl[i] = sd[tid] - v;
    if (tid == 1023) bsum[blockIdx.x] = sd[1023];
}

__global__ void scan_top_kernel(int* __restrict__ bsum, int nblk) {
    if (threadIdx.x == 0 && blockIdx.x == 0) {
        int run = 0;
        for (int b = 0; b < nblk; ++b) {
            int t = bsum[b];
            bsum[b] = run;
            run += t;
        }
    }
}

__global__ __launch_bounds__(256) void scan_add_kernel(int* __restrict__ row_ptr,
                                                       const int* __restrict__ bsum,
                                                       int N, int E) {
    int i = blockIdx.x * 256 + threadIdx.x;
    if (i < N) row_ptr[i] += bsum[i >> 10];
    if (i == 0) row_ptr[N] = E;
}

__global__ __launch_bounds__(256) void scatter_kernel(const int* __restrict__ dst,
                                                      const int* __restrict__ row_ptr,
                                                      int* __restrict__ cur,
                                                      int* __restrict__ eidx, int E) {
    int i = blockIdx.x * 256 + threadIdx.x;
    if (i < E) {
        int d = dst[i];
        int pos = atomicAdd(&cur[d], 1);
        eidx[row_ptr[d] + pos] = i;
    }
}

// ---------------- CSR softmax: esc scores -> normalized weights, in place ----------------
// wave-per-node; lane=(slot,h), NS=64/GH slots; each (edge,head) exp computed once;
// max/denom shfl_xor-reduced across slots (masks GH..32).
template <int GH>
__global__ __launch_bounds__(256) void csr_softmax_kernel(
    const int* __restrict__ row_ptr, const int* __restrict__ eidx,
    float* __restrict__ esc, int N) {
    constexpr int NS = 64 / GH;
    const int wid = threadIdx.x >> 6;
    const int lane = threadIdx.x & 63;
    const int nid = blockIdx.x * 4 + wid;
    if (nid >= N) return;
    const int r0 = row_ptr[nid], r1 = row_ptr[nid + 1];
    const int h = lane & (GH - 1);
    const int slot = lane / GH;

    float mx = -1e30f;
    for (int i = r0 + slot; i < r1; i += NS)
        mx = fmaxf(mx, esc[(size_t)eidx[i] * GH + h]);
#pragma unroll
    for (int m = GH; m < 64; m <<= 1) mx = fmaxf(mx, __shfl_xor(mx, m, 64));

    float den = 0.f;
    for (int i = r0 + slot; i < r1; i += NS)
        den += expf(esc[(size_t)eidx[i] * GH + h] - mx);
#pragma unroll
    for (int m = GH; m < 64; m <<= 1) den += __shfl_xor(den, m, 64);
    const float rden = 1.f / den;

    for (int i = r0 + slot; i < r1; i += NS) {
        size_t p = (size_t)eidx[i] * GH + h;
        esc[p] = expf(esc[p] - mx) * rden;
    }
}

// ---------------- node aggregation (weights precomputed): pure gather-sum ----------------
template <int Fn, int GH>
__global__ __launch_bounds__(256) void node_agg_kernel(
    const int* __restrict__ row_ptr, const int* __restrict__ eidx,
    const int* __restrict__ src,
    const float* __restrict__ w,      // [E, GH] softmax weights
    const float* __restrict__ Pnode,  // [N, GH*Fn]
    float* __restrict__ outp,         // [N, Fn]
    int N, int accum) {
    const int wid = threadIdx.x >> 6;
    const int lane = threadIdx.x & 63;
    const int nid = blockIdx.x * 4 + wid;
    if (nid >= N) return;
    const int r0 = row_ptr[nid], r1 = row_ptr[nid + 1];
    const int c0 = lane, c1 = lane + 64;

    float acc0 = 0.f, acc1 = 0.f;
    for (int i = r0; i < r1; ++i) {
        const int e = eidx[i];
        const float* wp = w + (size_t)e * GH;
        const float* pr = Pnode + (size_t)src[e] * GH * Fn;
#pragma unroll
        for (int h = 0; h < GH; ++h) {
            float wt = wp[h];
            if (c0 < Fn) acc0 += wt * pr[h * Fn + c0];
            if (Fn > 64 && c1 < Fn) acc1 += wt * pr[h * Fn + c1];
        }
    }
    if (c0 < Fn) {
        float* p = &outp[(size_t)nid * Fn + c0];
        *p = accum ? (*p + acc0) : acc0;
    }
    if (Fn > 64 && c1 < Fn) {
        float* p = &outp[(size_t)nid * Fn + c1];
        *p = accum ? (*p + acc1) : acc1;
    }
}

// ---------------- readout ----------------
__global__ __launch_bounds__(256) void readout_kernel(const float* __restrict__ nfb,
                                                      const float* __restrict__ y22p,
                                                      const float* __restrict__ Wr1,
                                                      const float* __restrict__ br1,
                                                      const float* __restrict__ Wr2,
                                                      const float* __restrict__ br2,
                                                      float* __restrict__ out) {
    const int b = blockIdx.x;
    const int t = threadIdx.x;
    __shared__ float y[128];
    __shared__ float hh[128];
    __shared__ float red[128];
    if (t < 92) {
        float s = 0.f;
        const float* base = nfb + (size_t)b * 600 * 92 + t;
        for (int i = 0; i < 600; ++i) s += base[(size_t)i * 92];
        y[t] = s * (1.f / 600.f);
    } else if (t >= 128 && t < 164) {
        int f = t - 128;
        float s = 0.f;
        const float* base = y22p + (size_t)b * 1200 * 36 + f;
        for (int i = 0; i < 1200; ++i) s += base[(size_t)i * 36];
        y[92 + f] = s * (1.f / 1200.f);
    }
    __syncthreads();
    if (t < 128) {
        float s = br1[t];
        for (int c = 0; c < 128; ++c) s += y[c] * Wr1[(size_t)c * 128 + t];
        hh[t] = sigmoidf(s);
    }
    __syncthreads();
    if (t < 128) red[t] = hh[t] * Wr2[t];
    __syncthreads();
    for (int k = 64; k > 0; k >>= 1) {
        if (t < k) red[t] += red[t + k];
        __syncthreads();
    }
    if (t == 0) out[b] = sigmoidf(red[0] + br2[0]);
}

// ---------------- host side ----------------
static inline int cdiv(int a, int b) { return (a + b - 1) / b; }

extern "C" void kernel_launch(void* const* d_in, const int* in_sizes, int n_in,
                              void* d_out, int out_size, void* d_ws, size_t ws_size,
                              hipStream_t stream) {
    const int* gg_src = (const int*)d_in[0];
    const int* gg_dst = (const int*)d_in[1];
    const float* gg_nf = (const float*)d_in[2];
    const float* gg_ef = (const float*)d_in[3];
    const int* lg_src = (const int*)d_in[4];
    const int* lg_dst = (const int*)d_in[5];
    const float* lg_nf = (const float*)d_in[6];
    const float* lg_ef = (const float*)d_in[7];
    const float* W_node1 = (const float*)d_in[8];
    const float* b_node1 = (const float*)d_in[9];
    const float* W_ni1 = (const float*)d_in[10];
    const float* W_nj1 = (const float*)d_in[11];
    const float* W_fij1 = (const float*)d_in[12];
    const float* attn1 = (const float*)d_in[13];
    const float* bias1 = (const float*)d_in[14];
    const float* W_node2a = (const float*)d_in[15];
    const float* b_node2a = (const float*)d_in[16];
    const float* W_ni2a = (const float*)d_in[17];
    const float* W_nj2a = (const float*)d_in[18];
    const float* W_fij2a = (const float*)d_in[19];
    const float* attn2a = (const float*)d_in[20];
    const float* bias2a = (const float*)d_in[21];
    const float* W_node2b = (const float*)d_in[22];
    const float* b_node2b = (const float*)d_in[23];
    const float* W_ni2b = (const float*)d_in[24];
    const float* W_nj2b = (const float*)d_in[25];
    const float* W_fij2b = (const float*)d_in[26];
    const float* attn2b = (const float*)d_in[27];
    const float* bias2b = (const float*)d_in[28];
    const float* Wr1 = (const float*)d_in[29];
    const float* br1 = (const float*)d_in[30];
    const float* Wr2 = (const float*)d_in[31];
    const float* br2 = (const float*)d_in[32];
    float* out = (float*)d_out;

    char* ws = (char*)d_ws;
    size_t off = 0;
    auto take = [&](size_t bytes) {
        size_t o = off;
        off += (bytes + 255) & ~(size_t)255;
        return (void*)(ws + o);
    };
    float* y2n = (float*)take((size_t)NG * 40 * 4);
    float* y22p = (float*)take((size_t)NG * 36 * 4);
    float* nfa = (float*)take((size_t)NL * 92 * 4);
    float* efa = (float*)take((size_t)EL * 40 * 4);
    float* nfb = (float*)take((size_t)NL * 92 * 4);
    float* esc = (float*)take((size_t)EG * 4 * 4);        // EG*4 == EL*8
    int* gg_row = (int*)take((size_t)(NG + 1) * 4);
    int* gg_eidx = (int*)take((size_t)EG * 4);
    int* gg_cnt = (int*)take((size_t)NG * 4);
    int* lg_row = (int*)take((size_t)(NL + 1) * 4);
    int* lg_eidx = (int*)take((size_t)EL * 4);
    int* lg_cnt = (int*)take((size_t)NL * 4);
    int* bsum = (int*)take((size_t)128 * 4);
    float* slab = (float*)take(2 * (size_t)NG * 288 * 4);  // 176.9 MB

    auto gemm = [&](const float* A, const float* Aadd, int e0, const float* W, int ldw,
                    const float* bias, float* C, int M, int K, int Nsub) {
        dim3 grid(M / 64, cdiv(Nsub, 64));
        gemm_kernel<<<grid, 256, 0, stream>>>(A, Aadd, e0, W, ldw, bias, C, M, K, Nsub);
    };
    auto build_csr = [&](const int* dst, int* row_ptr, int* eidx, int* cnt, int N, int E) {
        hipMemsetAsync(cnt, 0, (size_t)N * 4, stream);
        hist_kernel<<<cdiv(E, 256), 256, 0, stream>>>(dst, cnt, E);
        int nblk = cdiv(N, 1024);
        scan_block_kernel<<<nblk, 1024, 0, stream>>>(cnt, row_ptr, bsum, N);
        scan_top_kernel<<<1, 64, 0, stream>>>(bsum, nblk);
        scan_add_kernel<<<cdiv(N, 256), 256, 0, stream>>>(row_ptr, bsum, N, E);
        hipMemsetAsync(cnt, 0, (size_t)N * 4, stream);
        scatter_kernel<<<cdiv(E, 256), 256, 0, stream>>>(dst, row_ptr, cnt, eidx, E);
    };

    build_csr(gg_dst, gg_row, gg_eidx, gg_cnt, NG, EG);
    build_csr(lg_dst, lg_row, lg_eidx, lg_cnt, NL, EL);

    // ---------------- stage 1 (gg), 2 groups of 4 heads ----------------
    for (int g = 0; g < 2; ++g) {
        const int c0 = g * 144;     // 4 heads * FE=36
        const int c0n = g * 160;    // 4 heads * Fn=40
        float* Pni = slab;                               // NG*144
        float* Pnj = slab + (size_t)NG * 144;
        float* Pe = slab + 2 * (size_t)NG * 144;         // 153600*144 chunk
        gemm(gg_nf, nullptr, 0, W_ni1 + c0, 288, bias1 + c0, Pni, NG, 40, 144);
        gemm(gg_nf, nullptr, 0, W_nj1 + c0, 288, nullptr, Pnj, NG, 40, 144);
        for (int ch = 0; ch < 2; ++ch) {
            const int e0 = ch * 153600;
            gemm(gg_ef + (size_t)e0 * 10, nullptr, 0, W_fij1 + c0, 288, nullptr,
                 Pe, 153600, 10, 144);
            edge_combine_kernel<36, true><<<153600 / 4, 256, 0, stream>>>(
                gg_src, gg_dst, Pni, Pnj, Pe, 4, attn1 + c0, esc, y22p, e0, 153600, NG, g);
        }
        csr_softmax_kernel<4><<<NG / 4, 256, 0, stream>>>(gg_row, gg_eidx, esc, NG);
        float* Pnode = slab;   // alias: Pni/Pnj/Pe dead
        gemm(gg_nf, nullptr, 0, W_node1 + c0n, 320, b_node1 + c0n, Pnode, NG, 40, 160);
        node_agg_kernel<40, 4><<<NG / 4, 256, 0, stream>>>(gg_row, gg_eidx, gg_src, esc,
                                                           Pnode, y2n, NG, g);
    }

    // ---------------- stage 2 (lg), GH=8, two layers ----------------
    for (int layer = 0; layer < 2; ++layer) {
        const bool a = (layer == 0);
        const float* nf_in = a ? lg_nf : nfa;
        const float* ef_in = a ? lg_ef : efa;
        const float* Wni = a ? W_ni2a : W_ni2b;
        const float* Wnj = a ? W_nj2a : W_nj2b;
        const float* Wfij = a ? W_fij2a : W_fij2b;
        const float* Wnode = a ? W_node2a : W_node2b;
        const float* bn = a ? b_node2a : b_node2b;
        const float* bs = a ? bias2a : bias2b;
        const float* at = a ? attn2a : attn2b;
        float* nf_out = a ? nfa : nfb;

        float* Pni = slab;                                // NL*320
        float* Pnj = slab + (size_t)NL * 320;
        float* Pe = slab + 2 * (size_t)NL * 320;          // 38400*320 chunk
        gemm(nf_in, nullptr, 0, Wni, 320, bs, Pni, NL, 92, 320);
        gemm(nf_in, nullptr, 0, Wnj, 320, nullptr, Pnj, NL, 92, 320);
        for (int ch = 0; ch < 4; ++ch) {
            const int e0 = ch * 38400;
            gemm(ef_in + (size_t)e0 * 40, a ? y2n : nullptr, e0, Wfij, 320, nullptr,
                 Pe, 38400, 40, 320);
            if (a)
                edge_combine_kernel<40, true><<<38400 / 4, 256, 0, stream>>>(
                    lg_src, lg_dst, Pni, Pnj, Pe, 8, at, esc, efa, e0, 38400, EL, 0);
            else
                edge_combine_kernel<40, false><<<38400 / 4, 256, 0, stream>>>(
                    lg_src, lg_dst, Pni, Pnj, Pe, 8, at, esc, nullptr, e0, 38400, 0, 0);
        }
        csr_softmax_kernel<8><<<NL / 4, 256, 0, stream>>>(lg_row, lg_eidx, esc, NL);
        float* Pnode = slab;   // alias: Pni/Pnj/Pe dead
        gemm(nf_in, nullptr, 0, Wnode, 736, bn, Pnode, NL, 92, 736);
        node_agg_kernel<92, 8><<<NL / 4, 256, 0, stream>>>(lg_row, lg_eidx, lg_src, esc,
                                                           Pnode, nf_out, NL, 0);
    }

    // ---------------- readout ----------------
    readout_kernel<<<NB, 256, 0, stream>>>(nfb, y22p, Wr1, br1, Wr2, br2, out);
}

// Round 7
// 1775.123 us; speedup vs baseline: 1.7644x; 1.2815x over previous
//
#include <hip/hip_runtime.h>
#include <math.h>

#define NG 76800
#define EG 307200
#define NL 38400
#define EL 153600
#define NB 64
#define NH 8

typedef __attribute__((ext_vector_type(8))) short bf16x8;
typedef __attribute__((ext_vector_type(4))) float f32x4;
typedef unsigned short u16;

__device__ __forceinline__ float sigmoidf(float x) { return 1.f / (1.f + expf(-x)); }
__device__ __forceinline__ u16 f2bf(float x) {
    unsigned u = __float_as_uint(x);
    return (u16)((u + 0x7FFFu + ((u >> 16) & 1u)) >> 16);
}
__device__ __forceinline__ float bf2f(u16 v) { return __uint_as_float(((unsigned)v) << 16); }

// ---------------- fp32 -> padded bf16 [M x Kpad] ----------------
__global__ __launch_bounds__(256) void convert_pad_kernel(const float* __restrict__ src,
                                                          u16* __restrict__ dst,
                                                          int M, int K, int Kpad) {
    int i = blockIdx.x * 256 + threadIdx.x;
    if (i >= M * Kpad) return;
    int m = i / Kpad, k = i - m * Kpad;
    dst[i] = (k < K) ? f2bf(src[(size_t)m * K + k]) : (u16)0;
}

// ---------------- W[K x Nfull] -> bf16 Wt[Nalloc x Kpad] (zero padded) ----------------
__global__ __launch_bounds__(256) void wtrans_kernel(const float* __restrict__ W, int ldw,
                                                     u16* __restrict__ dst,
                                                     int K, int N, int Nalloc, int Kpad) {
    int i = blockIdx.x * 256 + threadIdx.x;
    if (i >= Nalloc * Kpad) return;
    int n = i / Kpad, k = i - n * Kpad;
    dst[i] = (n < N && k < K) ? f2bf(W[(size_t)k * ldw + n]) : (u16)0;
}

// ---------------- LDS-free bf16 MFMA GEMM ----------------
// C[M x Ncols](bf16) = A[M x KPAD](bf16) @ Wt[. x KPAD](bf16, row n = col n) (+bias fp32)
// grid (M/64, ceil(Ncols/64)); fragments loaded straight from global.
template <int KPAD>
__global__ __launch_bounds__(256) void gemm_bf_kernel(const u16* __restrict__ A,
                                                      const u16* __restrict__ Wt,
                                                      const float* __restrict__ bias,
                                                      u16* __restrict__ C, int Ncols) {
    const int m0 = blockIdx.x * 64;
    const int n0 = blockIdx.y * 64;
    const int wv = threadIdx.x >> 6;
    const int lane = threadIdx.x & 63;
    const int q = lane >> 4;
    const int mr = lane & 15;

    const u16* Arow = A + (size_t)(m0 + wv * 16 + mr) * KPAD;
    f32x4 acc[4];
#pragma unroll
    for (int t = 0; t < 4; ++t) acc[t] = (f32x4){0.f, 0.f, 0.f, 0.f};

#pragma unroll
    for (int k0 = 0; k0 < KPAD; k0 += 32) {
        bf16x8 af = *(const bf16x8*)(Arow + k0 + q * 8);
#pragma unroll
        for (int t = 0; t < 4; ++t) {
            bf16x8 bv = *(const bf16x8*)(Wt + (size_t)(n0 + t * 16 + mr) * KPAD + k0 + q * 8);
            acc[t] = __builtin_amdgcn_mfma_f32_16x16x32_bf16(af, bv, acc[t], 0, 0, 0);
        }
    }

#pragma unroll
    for (int t = 0; t < 4; ++t) {
        int col = n0 + t * 16 + mr;
        if (col < Ncols) {
            float b = bias ? bias[col] : 0.f;
#pragma unroll
            for (int r = 0; r < 4; ++r) {
                int row = m0 + wv * 16 + q * 4 + r;
                C[(size_t)row * Ncols + col] = f2bf(acc[t][r] + b);
            }
        }
    }
}

// ---------------- ef2a = bf16(lg_ef + repeat(y2n,2)), padded to 64 ----------------
__global__ __launch_bounds__(256) void ef2a_kernel(const float* __restrict__ lg_ef,
                                                   const float* __restrict__ y2n,
                                                   u16* __restrict__ dst) {
    int i = blockIdx.x * 256 + threadIdx.x;
    if (i >= EL * 64) return;
    int e = i >> 6, c = i & 63;
    dst[i] = (c < 40) ? f2bf(lg_ef[(size_t)e * 40 + c] + y2n[(size_t)(e >> 1) * 40 + c]) : (u16)0;
}

// ---------------- edge combine: wave-per-edge (bf16 tables) ----------------
// FSMODE: 0 none; 1 fp32 fsum [fsumE x FE] with accum flag; 2 bf16 fsum stride 64
template <int FE, int FSMODE>
__global__ __launch_bounds__(256) void edge_combine_kernel(
    const int* __restrict__ src, const int* __restrict__ dst,
    const u16* __restrict__ Pni, const u16* __restrict__ Pnj,
    const u16* __restrict__ Pe, int GH,
    const float* __restrict__ attn,
    float* __restrict__ esc,
    void* __restrict__ fsum,
    int e0, int CH, int fsumE, int accum) {
    const int wid = threadIdx.x >> 6;
    const int lane = threadIdx.x & 63;
    const int idx = blockIdx.x * 4 + wid;
    if (idx >= CH) return;
    const int e = e0 + idx;
    const int L = 64 / GH;
    const int h = lane / L;
    const int lam = lane - h * L;
    const int q = FE / L, rr = FE - q * L;
    const int cnt = (lam < rr) ? q + 1 : q;
    const int f0 = lam * q + (lam < rr ? lam : rr);
    const int cbase = h * FE + f0;
    const int cols = GH * FE;

    const u16* pi = Pni + (size_t)src[e] * cols;
    const u16* pj = Pnj + (size_t)dst[e] * cols;
    const u16* pe = Pe + (size_t)idx * cols;

    float vj[5];
    float eh = 0.f;
#pragma unroll
    for (int j = 0; j < 5; ++j) {
        vj[j] = 0.f;
        if (j < cnt) {
            const int c = cbase + j;
            float v = bf2f(pe[c]) + bf2f(pi[c]) + bf2f(pj[c]);
            v = v > 0.f ? v : 0.01f * v;   // leaky_relu(0.01)
            eh += v * attn[c];
            vj[j] = v;
        }
    }
    for (int m = 1; m < L; m <<= 1) eh += __shfl_xor(eh, m, 64);
    if (lam == 0) esc[(size_t)e * GH + h] = eh;
    if (FSMODE != 0 && e < fsumE) {
#pragma unroll
        for (int j = 0; j < 5; ++j) {
            float vs = vj[j];
            for (int m = L; m < 64; m <<= 1) vs += __shfl_xor(vs, m, 64);
            if (h == 0 && j < cnt) {
                if (FSMODE == 1) {
                    float* p = (float*)fsum + (size_t)e * FE + f0 + j;
                    *p = accum ? (*p + vs) : vs;
                } else {
                    ((u16*)fsum)[(size_t)e * 64 + f0 + j] = f2bf(vs);
                }
            }
        }
    }
}

// ---------------- CSR build ----------------
__global__ __launch_bounds__(256) void hist_kernel(const int* __restrict__ dst,
                                                   int* __restrict__ cnt, int E) {
    int i = blockIdx.x * 256 + threadIdx.x;
    if (i < E) atomicAdd(&cnt[dst[i]], 1);
}

__global__ __launch_bounds__(1024) void scan_block_kernel(const int* __restrict__ cnt,
                                                          int* __restrict__ excl,
                                                          int* __restrict__ bsum, int N) {
    __shared__ int sd[1024];
    const int tid = threadIdx.x;
    const int i = blockIdx.x * 1024 + tid;
    int v = (i < N) ? cnt[i] : 0;
    sd[tid] = v;
    __syncthreads();
    for (int off = 1; off < 1024; off <<= 1) {
        int t = (tid >= off) ? sd[tid - off] : 0;
        __syncthreads();
        sd[tid] += t;
        __syncthreads();
    }
    if (i < N) excl[i] = sd[tid] - v;
    if (tid == 1023) bsum[blockIdx.x] = sd[1023];
}

__global__ void scan_top_kernel(int* __restrict__ bsum, int nblk) {
    if (threadIdx.x == 0 && blockIdx.x == 0) {
        int run = 0;
        for (int b = 0; b < nblk; ++b) {
            int t = bsum[b];
            bsum[b] = run;
            run += t;
        }
    }
}

__global__ __launch_bounds__(256) void scan_add_kernel(int* __restrict__ row_ptr,
                                                       const int* __restrict__ bsum,
                                                       int N, int E) {
    int i = blockIdx.x * 256 + threadIdx.x;
    if (i < N) row_ptr[i] += bsum[i >> 10];
    if (i == 0) row_ptr[N] = E;
}

__global__ __launch_bounds__(256) void scatter_kernel(const int* __restrict__ dst,
                                                      const int* __restrict__ row_ptr,
                                                      int* __restrict__ cur,
                                                      int* __restrict__ eidx, int E) {
    int i = blockIdx.x * 256 + threadIdx.x;
    if (i < E) {
        int d = dst[i];
        int pos = atomicAdd(&cur[d], 1);
        eidx[row_ptr[d] + pos] = i;
    }
}

// ---------------- CSR softmax: scores -> normalized weights, in place ----------------
template <int GH>
__global__ __launch_bounds__(256) void csr_softmax_kernel(
    const int* __restrict__ row_ptr, const int* __restrict__ eidx,
    float* __restrict__ esc, int N) {
    constexpr int NS = 64 / GH;
    const int wid = threadIdx.x >> 6;
    const int lane = threadIdx.x & 63;
    const int nid = blockIdx.x * 4 + wid;
    if (nid >= N) return;
    const int r0 = row_ptr[nid], r1 = row_ptr[nid + 1];
    const int h = lane & (GH - 1);
    const int slot = lane / GH;

    float mx = -1e30f;
    for (int i = r0 + slot; i < r1; i += NS)
        mx = fmaxf(mx, esc[(size_t)eidx[i] * GH + h]);
#pragma unroll
    for (int m = GH; m < 64; m <<= 1) mx = fmaxf(mx, __shfl_xor(mx, m, 64));

    float den = 0.f;
    for (int i = r0 + slot; i < r1; i += NS)
        den += expf(esc[(size_t)eidx[i] * GH + h] - mx);
#pragma unroll
    for (int m = GH; m < 64; m <<= 1) den += __shfl_xor(den, m, 64);
    const float rden = 1.f / den;

    for (int i = r0 + slot; i < r1; i += NS) {
        size_t p = (size_t)eidx[i] * GH + h;
        esc[p] = expf(esc[p] - mx) * rden;
    }
}

// ---------------- node aggregation: pure gather-sum (bf16 Pnode) ----------------
// OM 0: fp32 out stride Fn, accum flag. OM 1: bf16 out stride 96, zero-padded 92..95.
template <int Fn, int GH, int OM>
__global__ __launch_bounds__(256) void node_agg_kernel(
    const int* __restrict__ row_ptr, const int* __restrict__ eidx,
    const int* __restrict__ src,
    const float* __restrict__ w,      // [E, GH] softmax weights
    const u16* __restrict__ Pnode,    // [N, GH*Fn] bf16
    void* __restrict__ outp,
    int N, int accum) {
    const int wid = threadIdx.x >> 6;
    const int lane = threadIdx.x & 63;
    const int nid = blockIdx.x * 4 + wid;
    if (nid >= N) return;
    const int r0 = row_ptr[nid], r1 = row_ptr[nid + 1];
    const int c0 = lane, c1 = lane + 64;

    float acc0 = 0.f, acc1 = 0.f;
    for (int i = r0; i < r1; ++i) {
        const int e = eidx[i];
        const float* wp = w + (size_t)e * GH;
        const u16* pr = Pnode + (size_t)src[e] * GH * Fn;
#pragma unroll
        for (int h = 0; h < GH; ++h) {
            float wt = wp[h];
            if (c0 < Fn) acc0 += wt * bf2f(pr[h * Fn + c0]);
            if (Fn > 64 && c1 < Fn) acc1 += wt * bf2f(pr[h * Fn + c1]);
        }
    }
    if (OM == 0) {
        float* o = (float*)outp + (size_t)nid * Fn;
        if (c0 < Fn) o[c0] = accum ? (o[c0] + acc0) : acc0;
        if (Fn > 64 && c1 < Fn) o[c1] = accum ? (o[c1] + acc1) : acc1;
    } else {
        u16* o = (u16*)outp + (size_t)nid * 96;
        if (c0 < Fn) o[c0] = f2bf(acc0);
        if (c1 < Fn) o[c1] = f2bf(acc1);
        else if (c1 < 96) o[c1] = 0;
    }
}

// ---------------- readout (nfb in bf16 stride 96) ----------------
__global__ __launch_bounds__(256) void readout_kernel(const u16* __restrict__ nfb,
                                                      const float* __restrict__ y22p,
                                                      const float* __restrict__ Wr1,
                                                      const float* __restrict__ br1,
                                                      const float* __restrict__ Wr2,
                                                      const float* __restrict__ br2,
                                                      float* __restrict__ out) {
    const int b = blockIdx.x;
    const int t = threadIdx.x;
    __shared__ float y[128];
    __shared__ float hh[128];
    __shared__ float red[128];
    if (t < 92) {
        float s = 0.f;
        const u16* base = nfb + (size_t)b * 600 * 96 + t;
        for (int i = 0; i < 600; ++i) s += bf2f(base[(size_t)i * 96]);
        y[t] = s * (1.f / 600.f);
    } else if (t >= 128 && t < 164) {
        int f = t - 128;
        float s = 0.f;
        const float* base = y22p + (size_t)b * 1200 * 36 + f;
        for (int i = 0; i < 1200; ++i) s += base[(size_t)i * 36];
        y[92 + f] = s * (1.f / 1200.f);
    }
    __syncthreads();
    if (t < 128) {
        float s = br1[t];
        for (int c = 0; c < 128; ++c) s += y[c] * Wr1[(size_t)c * 128 + t];
        hh[t] = sigmoidf(s);
    }
    __syncthreads();
    if (t < 128) red[t] = hh[t] * Wr2[t];
    __syncthreads();
    for (int k = 64; k > 0; k >>= 1) {
        if (t < k) red[t] += red[t + k];
        __syncthreads();
    }
    if (t == 0) out[b] = sigmoidf(red[0] + br2[0]);
}

// ---------------- host side ----------------
static inline int cdiv(int a, int b) { return (a + b - 1) / b; }

extern "C" void kernel_launch(void* const* d_in, const int* in_sizes, int n_in,
                              void* d_out, int out_size, void* d_ws, size_t ws_size,
                              hipStream_t stream) {
    const int* gg_src = (const int*)d_in[0];
    const int* gg_dst = (const int*)d_in[1];
    const float* gg_nf = (const float*)d_in[2];
    const float* gg_ef = (const float*)d_in[3];
    const int* lg_src = (const int*)d_in[4];
    const int* lg_dst = (const int*)d_in[5];
    const float* lg_nf = (const float*)d_in[6];
    const float* lg_ef = (const float*)d_in[7];
    const float* W_node1 = (const float*)d_in[8];
    const float* b_node1 = (const float*)d_in[9];
    const float* W_ni1 = (const float*)d_in[10];
    const float* W_nj1 = (const float*)d_in[11];
    const float* W_fij1 = (const float*)d_in[12];
    const float* attn1 = (const float*)d_in[13];
    const float* bias1 = (const float*)d_in[14];
    const float* W_node2a = (const float*)d_in[15];
    const float* b_node2a = (const float*)d_in[16];
    const float* W_ni2a = (const float*)d_in[17];
    const float* W_nj2a = (const float*)d_in[18];
    const float* W_fij2a = (const float*)d_in[19];
    const float* attn2a = (const float*)d_in[20];
    const float* bias2a = (const float*)d_in[21];
    const float* W_node2b = (const float*)d_in[22];
    const float* b_node2b = (const float*)d_in[23];
    const float* W_ni2b = (const float*)d_in[24];
    const float* W_nj2b = (const float*)d_in[25];
    const float* W_fij2b = (const float*)d_in[26];
    const float* attn2b = (const float*)d_in[27];
    const float* bias2b = (const float*)d_in[28];
    const float* Wr1 = (const float*)d_in[29];
    const float* br1 = (const float*)d_in[30];
    const float* Wr2 = (const float*)d_in[31];
    const float* br2 = (const float*)d_in[32];
    float* out = (float*)d_out;

    char* ws = (char*)d_ws;
    size_t off = 0;
    auto take = [&](size_t bytes) {
        size_t o = off;
        off += (bytes + 255) & ~(size_t)255;
        return (void*)(ws + o);
    };
    float* y2n = (float*)take((size_t)NG * 40 * 4);
    float* y22p = (float*)take((size_t)NG * 36 * 4);
    float* esc = (float*)take((size_t)EG * 4 * 4);        // EG*4 == EL*8
    int* gg_row = (int*)take((size_t)(NG + 1) * 4);
    int* gg_eidx = (int*)take((size_t)EG * 4);
    int* gg_cnt = (int*)take((size_t)NG * 4);
    int* lg_row = (int*)take((size_t)(NL + 1) * 4);
    int* lg_eidx = (int*)take((size_t)EL * 4);
    int* lg_cnt = (int*)take((size_t)NL * 4);
    int* bsum = (int*)take((size_t)128 * 4);
    u16* gg_nf_bf = (u16*)take((size_t)NG * 64 * 2);
    u16* gg_ef_bf = (u16*)take((size_t)EG * 32 * 2);
    u16* lg_nf_bf = (u16*)take((size_t)NL * 96 * 2);
    u16* nfa_bf = (u16*)take((size_t)NL * 96 * 2);
    u16* nfb_bf = (u16*)take((size_t)NL * 96 * 2);
    u16* ef2a_bf = (u16*)take((size_t)EL * 64 * 2);
    u16* efa_bf = (u16*)take((size_t)EL * 64 * 2);
    u16* wt_ni1 = (u16*)take((size_t)384 * 64 * 2);
    u16* wt_nj1 = (u16*)take((size_t)384 * 64 * 2);
    u16* wt_node1 = (u16*)take((size_t)384 * 64 * 2);
    u16* wt_fij1 = (u16*)take((size_t)384 * 32 * 2);
    u16* wt_ni2a = (u16*)take((size_t)320 * 96 * 2);
    u16* wt_nj2a = (u16*)take((size_t)320 * 96 * 2);
    u16* wt_ni2b = (u16*)take((size_t)320 * 96 * 2);
    u16* wt_nj2b = (u16*)take((size_t)320 * 96 * 2);
    u16* wt_fij2a = (u16*)take((size_t)320 * 64 * 2);
    u16* wt_fij2b = (u16*)take((size_t)320 * 64 * 2);
    u16* wt_node2a = (u16*)take((size_t)768 * 96 * 2);
    u16* wt_node2b = (u16*)take((size_t)768 * 96 * 2);
    u16* slab = (u16*)take(2 * (size_t)NG * 288 * 2);     // 44.24M shorts, 88.5 MB

    auto cvt = [&](const float* s, u16* d, int M, int K, int Kpad) {
        convert_pad_kernel<<<cdiv(M * Kpad, 256), 256, 0, stream>>>(s, d, M, K, Kpad);
    };
    auto wtr = [&](const float* W, int ldw, u16* d, int K, int N, int Nalloc, int Kpad) {
        wtrans_kernel<<<cdiv(Nalloc * Kpad, 256), 256, 0, stream>>>(W, ldw, d, K, N, Nalloc, Kpad);
    };
    auto build_csr = [&](const int* dst, int* row_ptr, int* eidx, int* cnt, int N, int E) {
        hipMemsetAsync(cnt, 0, (size_t)N * 4, stream);
        hist_kernel<<<cdiv(E, 256), 256, 0, stream>>>(dst, cnt, E);
        int nblk = cdiv(N, 1024);
        scan_block_kernel<<<nblk, 1024, 0, stream>>>(cnt, row_ptr, bsum, N);
        scan_top_kernel<<<1, 64, 0, stream>>>(bsum, nblk);
        scan_add_kernel<<<cdiv(N, 256), 256, 0, stream>>>(row_ptr, bsum, N, E);
        hipMemsetAsync(cnt, 0, (size_t)N * 4, stream);
        scatter_kernel<<<cdiv(E, 256), 256, 0, stream>>>(dst, row_ptr, cnt, eidx, E);
    };

    build_csr(gg_dst, gg_row, gg_eidx, gg_cnt, NG, EG);
    build_csr(lg_dst, lg_row, lg_eidx, lg_cnt, NL, EL);

    cvt(gg_nf, gg_nf_bf, NG, 40, 64);
    cvt(gg_ef, gg_ef_bf, EG, 10, 32);
    cvt(lg_nf, lg_nf_bf, NL, 92, 96);
    wtr(W_ni1, 288, wt_ni1, 40, 288, 384, 64);
    wtr(W_nj1, 288, wt_nj1, 40, 288, 384, 64);
    wtr(W_node1, 320, wt_node1, 40, 320, 384, 64);
    wtr(W_fij1, 288, wt_fij1, 10, 288, 384, 32);
    wtr(W_ni2a, 320, wt_ni2a, 92, 320, 320, 96);
    wtr(W_nj2a, 320, wt_nj2a, 92, 320, 320, 96);
    wtr(W_ni2b, 320, wt_ni2b, 92, 320, 320, 96);
    wtr(W_nj2b, 320, wt_nj2b, 92, 320, 320, 96);
    wtr(W_fij2a, 320, wt_fij2a, 40, 320, 320, 64);
    wtr(W_fij2b, 320, wt_fij2b, 40, 320, 320, 64);
    wtr(W_node2a, 736, wt_node2a, 92, 736, 768, 96);
    wtr(W_node2b, 736, wt_node2b, 92, 736, 768, 96);
    hipMemsetAsync(efa_bf, 0, (size_t)EL * 64 * 2, stream);  // pad cols 40..63

    // ---------------- stage 1 (gg), 2 groups of 4 heads ----------------
    for (int g = 0; g < 2; ++g) {
        const int c0 = g * 144;     // 4 heads * FE=36
        const int c0n = g * 160;    // 4 heads * Fn=40
        u16* Pni = slab;                                  // NG*144
        u16* Pnj = slab + (size_t)NG * 144;
        u16* Pe = slab + 2 * (size_t)NG * 144;            // 153600*144 chunk
        gemm_bf_kernel<64><<<dim3(NG / 64, 3), 256, 0, stream>>>(
            gg_nf_bf, wt_ni1 + (size_t)c0 * 64, bias1 + c0, Pni, 144);
        gemm_bf_kernel<64><<<dim3(NG / 64, 3), 256, 0, stream>>>(
            gg_nf_bf, wt_nj1 + (size_t)c0 * 64, nullptr, Pnj, 144);
        for (int ch = 0; ch < 2; ++ch) {
            const int e0 = ch * 153600;
            gemm_bf_kernel<32><<<dim3(153600 / 64, 3), 256, 0, stream>>>(
                gg_ef_bf + (size_t)e0 * 32, wt_fij1 + (size_t)c0 * 32, nullptr, Pe, 144);
            edge_combine_kernel<36, 1><<<153600 / 4, 256, 0, stream>>>(
                gg_src, gg_dst, Pni, Pnj, Pe, 4, attn1 + c0, esc, y22p, e0, 153600, NG, g);
        }
        csr_softmax_kernel<4><<<NG / 4, 256, 0, stream>>>(gg_row, gg_eidx, esc, NG);
        u16* Pnode = slab;   // alias: Pni/Pnj/Pe dead
        gemm_bf_kernel<64><<<dim3(NG / 64, 3), 256, 0, stream>>>(
            gg_nf_bf, wt_node1 + (size_t)c0n * 64, b_node1 + c0n, Pnode, 160);
        node_agg_kernel<40, 4, 0><<<NG / 4, 256, 0, stream>>>(gg_row, gg_eidx, gg_src, esc,
                                                              Pnode, y2n, NG, g);
    }

    // ef for lg layer 2a: bf16(lg_ef + repeat(y2n,2)), padded
    ef2a_kernel<<<cdiv(EL * 64, 256), 256, 0, stream>>>(lg_ef, y2n, ef2a_bf);

    // ---------------- stage 2 (lg), GH=8, two layers ----------------
    for (int layer = 0; layer < 2; ++layer) {
        const bool a = (layer == 0);
        const u16* nf_in = a ? lg_nf_bf : nfa_bf;
        const u16* ef_in = a ? ef2a_bf : efa_bf;
        const u16* Wni = a ? wt_ni2a : wt_ni2b;
        const u16* Wnj = a ? wt_nj2a : wt_nj2b;
        const u16* Wfij = a ? wt_fij2a : wt_fij2b;
        const u16* Wnode = a ? wt_node2a : wt_node2b;
        const float* bn = a ? b_node2a : b_node2b;
        const float* bs = a ? bias2a : bias2b;
        const float* at = a ? attn2a : attn2b;
        u16* nf_out = a ? nfa_bf : nfb_bf;

        u16* Pni = slab;                                  // NL*320
        u16* Pnj = slab + (size_t)NL * 320;
        u16* Pe = slab + 2 * (size_t)NL * 320;            // 38400*320 chunk
        gemm_bf_kernel<96><<<dim3(NL / 64, 5), 256, 0, stream>>>(nf_in, Wni, bs, Pni, 320);
        gemm_bf_kernel<96><<<dim3(NL / 64, 5), 256, 0, stream>>>(nf_in, Wnj, nullptr, Pnj, 320);
        for (int ch = 0; ch < 4; ++ch) {
            const int e0 = ch * 38400;
            gemm_bf_kernel<64><<<dim3(38400 / 64, 5), 256, 0, stream>>>(
                ef_in + (size_t)e0 * 64, Wfij, nullptr, Pe, 320);
            if (a)
                edge_combine_kernel<40, 2><<<38400 / 4, 256, 0, stream>>>(
                    lg_src, lg_dst, Pni, Pnj, Pe, 8, at, esc, efa_bf, e0, 38400, EL, 0);
            else
                edge_combine_kernel<40, 0><<<38400 / 4, 256, 0, stream>>>(
                    lg_src, lg_dst, Pni, Pnj, Pe, 8, at, esc, nullptr, e0, 38400, 0, 0);
        }
        csr_softmax_kernel<8><<<NL / 4, 256, 0, stream>>>(lg_row, lg_eidx, esc, NL);
        u16* Pnode = slab;   // alias: Pni/Pnj/Pe dead
        gemm_bf_kernel<96><<<dim3(NL / 64, 12), 256, 0, stream>>>(nf_in, Wnode, bn, Pnode, 736);
        node_agg_kernel<92, 8, 1><<<NL / 4, 256, 0, stream>>>(lg_row, lg_eidx, lg_src, esc,
                                                              Pnode, nf_out, NL, 0);
    }

    // ---------------- readout ----------------
    readout_kernel<<<NB, 256, 0, stream>>>(nfb_bf, y22p, Wr1, br1, Wr2, br2, out);
}

// Round 9
// 1372.130 us; speedup vs baseline: 2.2826x; 1.2937x over previous
//
#include <hip/hip_runtime.h>
#include <math.h>

#define NG 76800
#define EG 307200
#define NL 38400
#define EL 153600
#define NB 64
#define NH 8

typedef __attribute__((ext_vector_type(8))) short bf16x8;
typedef __attribute__((ext_vector_type(4))) float f32x4;
typedef unsigned short u16;

__device__ __forceinline__ float sigmoidf(float x) { return 1.f / (1.f + expf(-x)); }
__device__ __forceinline__ u16 f2bf(float x) {
    unsigned u = __float_as_uint(x);
    return (u16)((u + 0x7FFFu + ((u >> 16) & 1u)) >> 16);
}
__device__ __forceinline__ float bf2f(u16 v) { return __uint_as_float(((unsigned)v) << 16); }

// ---------------- fp32 -> padded bf16 [M x Kpad] ----------------
__global__ __launch_bounds__(256) void convert_pad_kernel(const float* __restrict__ src,
                                                          u16* __restrict__ dst,
                                                          int M, int K, int Kpad) {
    int i = blockIdx.x * 256 + threadIdx.x;
    if (i >= M * Kpad) return;
    int m = i / Kpad, k = i - m * Kpad;
    dst[i] = (k < K) ? f2bf(src[(size_t)m * K + k]) : (u16)0;
}

// ---------------- W[K x Nfull] -> bf16 Wt[Nalloc x Kpad] (zero padded) ----------------
__global__ __launch_bounds__(256) void wtrans_kernel(const float* __restrict__ W, int ldw,
                                                     u16* __restrict__ dst,
                                                     int K, int N, int Nalloc, int Kpad) {
    int i = blockIdx.x * 256 + threadIdx.x;
    if (i >= Nalloc * Kpad) return;
    int n = i / Kpad, k = i - n * Kpad;
    dst[i] = (n < N && k < K) ? f2bf(W[(size_t)k * ldw + n]) : (u16)0;
}

// ---------------- head-padded transform: FE 36->40, 8 heads, R=320 rows ----------------
__global__ __launch_bounds__(256) void wtrans_hp_kernel(const float* __restrict__ W, int ldw,
                                                        u16* __restrict__ dst,
                                                        int K, int Kpad) {
    int i = blockIdx.x * 256 + threadIdx.x;
    if (i >= 320 * Kpad) return;
    int n = i / Kpad, k = i - n * Kpad;
    int hh = n / 40, f = n - hh * 40;
    float v = (k < K && f < 36) ? W[(size_t)k * ldw + hh * 36 + f] : 0.f;
    dst[i] = f2bf(v);
}

// ---------------- meta: padded attn1 + concat biases ----------------
__global__ __launch_bounds__(256) void meta_kernel(const float* __restrict__ attn1,
                                                   const float* __restrict__ bias1,
                                                   const float* __restrict__ b2a,
                                                   const float* __restrict__ b2b,
                                                   float* __restrict__ attn_p1,
                                                   float* __restrict__ bias_cat1,
                                                   float* __restrict__ bias_cat2a,
                                                   float* __restrict__ bias_cat2b) {
    int i = blockIdx.x * 256 + threadIdx.x;
    if (i < 320) {
        int hh = i / 40, f = i - hh * 40;
        attn_p1[i] = (f < 36) ? attn1[hh * 36 + f] : 0.f;
    } else if (i < 960) {
        int j = i - 320;
        float v = 0.f;
        if (j < 320) {
            int hh = j / 40, f = j - hh * 40;
            v = (f < 36) ? bias1[hh * 36 + f] : 0.f;
        }
        bias_cat1[j] = v;
    } else if (i < 1600) {
        int j = i - 960;
        bias_cat2a[j] = (j < 320) ? b2a[j] : 0.f;
    } else if (i < 2240) {
        int j = i - 1600;
        bias_cat2b[j] = (j < 320) ? b2b[j] : 0.f;
    }
}

// ---------------- LDS-free bf16 MFMA GEMM ----------------
template <int KPAD>
__global__ __launch_bounds__(256) void gemm_bf_kernel(const u16* __restrict__ A,
                                                      const u16* __restrict__ Wt,
                                                      const float* __restrict__ bias,
                                                      u16* __restrict__ C, int Ncols) {
    const int m0 = blockIdx.x * 64;
    const int n0 = blockIdx.y * 64;
    const int wv = threadIdx.x >> 6;
    const int lane = threadIdx.x & 63;
    const int q = lane >> 4;
    const int mr = lane & 15;

    const u16* Arow = A + (size_t)(m0 + wv * 16 + mr) * KPAD;
    f32x4 acc[4];
#pragma unroll
    for (int t = 0; t < 4; ++t) acc[t] = (f32x4){0.f, 0.f, 0.f, 0.f};

#pragma unroll
    for (int k0 = 0; k0 < KPAD; k0 += 32) {
        bf16x8 af = *(const bf16x8*)(Arow + k0 + q * 8);
#pragma unroll
        for (int t = 0; t < 4; ++t) {
            bf16x8 bv = *(const bf16x8*)(Wt + (size_t)(n0 + t * 16 + mr) * KPAD + k0 + q * 8);
            acc[t] = __builtin_amdgcn_mfma_f32_16x16x32_bf16(af, bv, acc[t], 0, 0, 0);
        }
    }

#pragma unroll
    for (int t = 0; t < 4; ++t) {
        int col = n0 + t * 16 + mr;
        if (col < Ncols) {
            float b = bias ? bias[col] : 0.f;
#pragma unroll
            for (int r = 0; r < 4; ++r) {
                int row = m0 + wv * 16 + q * 4 + r;
                C[(size_t)row * Ncols + col] = f2bf(acc[t][r] + b);
            }
        }
    }
}

// ---------------- ef2a = bf16(lg_ef + repeat(y2n,2)), padded to 64 ----------------
__global__ __launch_bounds__(256) void ef2a_kernel(const float* __restrict__ lg_ef,
                                                   const float* __restrict__ y2n,
                                                   u16* __restrict__ dst) {
    int i = blockIdx.x * 256 + threadIdx.x;
    if (i >= EL * 64) return;
    int e = i >> 6, c = i & 63;
    dst[i] = (c < 40) ? f2bf(lg_ef[(size_t)e * 40 + c] + y2n[(size_t)(e >> 1) * 40 + c]) : (u16)0;
}

// ---------------- edge combine: wave-per-edge, vectorized 16B loads ----------------
// Unified layout: 8 heads x 40 cols (stage1 head-padded 36->40).
// Pn[n][640]: ni cols 0..319, nj cols 320..639. Pe[idx][320].
// 40 active lanes: lane l -> head h=l/5, slot o=l%5, cols c=h*40+o*8 (one bf16x8).
// eh: 5 index-shfls within head. fsum (head-sum over h): 3-step XOR butterfly in h-space.
// FSMODE: 0 none; 1 fp32 out stride 36 (f<36, e<fsumE); 2 bf16 out stride 64 (e<fsumE).
template <int FSMODE>
__global__ __launch_bounds__(256) void edge_combine_kernel(
    const int* __restrict__ src, const int* __restrict__ dst,
    const u16* __restrict__ Pn, const u16* __restrict__ Pe,
    const float* __restrict__ attn,   // [320]
    float* __restrict__ esc,          // [E][8]
    void* __restrict__ fsum,
    int e0, int CH, int fsumE) {
    const int wid = threadIdx.x >> 6;
    const int lane = threadIdx.x & 63;
    const int idx = blockIdx.x * 4 + wid;
    if (idx >= CH) return;
    const int e = e0 + idx;
    const int lc = (lane < 40) ? lane : 39;
    const int h = lc / 5, o = lc - h * 5;
    const int c = h * 40 + o * 8;
    const bool act = (lane < 40);

    float attn_r[8];
#pragma unroll
    for (int j = 0; j < 8; ++j) attn_r[j] = attn[c + j];

    const int s = src[e], d = dst[e];
    bf16x8 api = *(const bf16x8*)(Pn + (size_t)s * 640 + c);
    bf16x8 apj = *(const bf16x8*)(Pn + (size_t)d * 640 + 320 + c);
    bf16x8 ape = *(const bf16x8*)(Pe + (size_t)idx * 320 + c);

    float v[8];
    float ehp = 0.f;
#pragma unroll
    for (int j = 0; j < 8; ++j) {
        float x = bf2f((u16)api[j]) + bf2f((u16)apj[j]) + bf2f((u16)ape[j]);
        x = x > 0.f ? x : 0.01f * x;   // leaky_relu(0.01)
        v[j] = x;
        ehp += x * attn_r[j];
    }
    float eh = 0.f;
#pragma unroll
    for (int k = 0; k < 5; ++k) eh += __shfl(ehp, h * 5 + k, 64);
    if (act && o == 0) esc[(size_t)e * 8 + h] = eh;

    if (FSMODE != 0 && e < fsumE) {
#pragma unroll
        for (int m = 4; m >= 1; m >>= 1) {
            const int p = (h ^ m) * 5 + o;
#pragma unroll
            for (int j = 0; j < 8; ++j) v[j] += __shfl(v[j], p, 64);
        }
        if (act && h == 0) {
#pragma unroll
            for (int j = 0; j < 8; ++j) {
                const int f = o * 8 + j;
                if (FSMODE == 1) {
                    if (f < 36) ((float*)fsum)[(size_t)e * 36 + f] = v[j];
                } else {
                    ((u16*)fsum)[(size_t)e * 64 + f] = f2bf(v[j]);
                }
            }
        }
    }
}

// ---------------- CSR build ----------------
__global__ __launch_bounds__(256) void hist_kernel(const int* __restrict__ dst,
                                                   int* __restrict__ cnt, int E) {
    int i = blockIdx.x * 256 + threadIdx.x;
    if (i < E) atomicAdd(&cnt[dst[i]], 1);
}

__global__ __launch_bounds__(1024) void scan_block_kernel(const int* __restrict__ cnt,
                                                          int* __restrict__ excl,
                                                          int* __restrict__ bsum, int N) {
    __shared__ int sd[1024];
    const int tid = threadIdx.x;
    const int i = blockIdx.x * 1024 + tid;
    int v = (i < N) ? cnt[i] : 0;
    sd[tid] = v;
    __syncthreads();
    for (int off = 1; off < 1024; off <<= 1) {
        int t = (tid >= off) ? sd[tid - off] : 0;
        __syncthreads();
        sd[tid] += t;
        __syncthreads();
    }
    if (i < N) excl[i] = sd[tid] - v;
    if (tid == 1023) bsum[blockIdx.x] = sd[1023];
}

__global__ void scan_top_kernel(int* __restrict__ bsum, int nblk) {
    if (threadIdx.x == 0 && blockIdx.x == 0) {
        int run = 0;
        for (int b = 0; b < nblk; ++b) {
            int t = bsum[b];
            bsum[b] = run;
            run += t;
        }
    }
}

__global__ __launch_bounds__(256) void scan_add_kernel(int* __restrict__ row_ptr,
                                                       const int* __restrict__ bsum,
                                                       int N, int E) {
    int i = blockIdx.x * 256 + threadIdx.x;
    if (i < N) row_ptr[i] += bsum[i >> 10];
    if (i == 0) row_ptr[N] = E;
}

__global__ __launch_bounds__(256) void scatter_kernel(const int* __restrict__ dst,
                                                      const int* __restrict__ row_ptr,
                                                      int* __restrict__ cur,
                                                      int* __restrict__ eidx, int E) {
    int i = blockIdx.x * 256 + threadIdx.x;
    if (i < E) {
        int d = dst[i];
        int pos = atomicAdd(&cur[d], 1);
        eidx[row_ptr[d] + pos] = i;
    }
}

// ---------------- CSR softmax: scores -> normalized weights, in place ----------------
template <int GH>
__global__ __launch_bounds__(256) void csr_softmax_kernel(
    const int* __restrict__ row_ptr, const int* __restrict__ eidx,
    float* __restrict__ esc, int N) {
    constexpr int NS = 64 / GH;
    const int wid = threadIdx.x >> 6;
    const int lane = threadIdx.x & 63;
    const int nid = blockIdx.x * 4 + wid;
    if (nid >= N) return;
    const int r0 = row_ptr[nid], r1 = row_ptr[nid + 1];
    const int h = lane & (GH - 1);
    const int slot = lane / GH;

    float mx = -1e30f;
    for (int i = r0 + slot; i < r1; i += NS)
        mx = fmaxf(mx, esc[(size_t)eidx[i] * GH + h]);
#pragma unroll
    for (int m = GH; m < 64; m <<= 1) mx = fmaxf(mx, __shfl_xor(mx, m, 64));

    float den = 0.f;
    for (int i = r0 + slot; i < r1; i += NS)
        den += expf(esc[(size_t)eidx[i] * GH + h] - mx);
#pragma unroll
    for (int m = GH; m < 64; m <<= 1) den += __shfl_xor(den, m, 64);
    const float rden = 1.f / den;

    for (int i = r0 + slot; i < r1; i += NS) {
        size_t p = (size_t)eidx[i] * GH + h;
        esc[p] = expf(esc[p] - mx) * rden;
    }
}

// ---------------- node aggregation: uint (2-col) gather-sum ----------------
// OM 0: fp32 out stride Fn. OM 1: bf16 out stride 96 zero-padded 92..95.
template <int Fn, int GH, int OM>
__global__ __launch_bounds__(256) void node_agg_kernel(
    const int* __restrict__ row_ptr, const int* __restrict__ eidx,
    const int* __restrict__ src,
    const float* __restrict__ w,      // [E, GH] softmax weights
    const u16* __restrict__ Pnode,    // [N, GH*Fn] bf16
    void* __restrict__ outp, int N) {
    constexpr int PAIRS = Fn / 2;     // Fn even: 20 / 46
    constexpr int STR = GH * Fn;
    const int wid = threadIdx.x >> 6;
    const int lane = threadIdx.x & 63;
    const int nid = blockIdx.x * 4 + wid;
    if (nid >= N) return;
    const int r0 = row_ptr[nid], r1 = row_ptr[nid + 1];
    const int col = 2 * lane;
    const bool act = (lane < PAIRS);

    float a0 = 0.f, a1 = 0.f;
    for (int i = r0; i < r1; ++i) {
        const int e = eidx[i];
        const float* wp = w + (size_t)e * GH;
        const u16* pr = Pnode + (size_t)src[e] * STR;
#pragma unroll
        for (int hh = 0; hh < GH; ++hh) {
            const float wt = wp[hh];
            if (act) {
                unsigned pv = *(const unsigned*)(pr + hh * Fn + col);
                a0 += wt * bf2f((u16)(pv & 0xFFFFu));
                a1 += wt * bf2f((u16)(pv >> 16));
            }
        }
    }
    if (OM == 0) {
        if (act) {
            float* op = (float*)outp + (size_t)nid * Fn + col;
            op[0] = a0;
            op[1] = a1;
        }
    } else {
        unsigned* ob = (unsigned*)((u16*)outp + (size_t)nid * 96);
        if (act) {
            unsigned pk = (unsigned)f2bf(a0) | ((unsigned)f2bf(a1) << 16);
            ob[lane] = pk;
        } else if (lane < 48) {
            ob[lane] = 0u;
        }
    }
}

// ---------------- readout ----------------
__global__ __launch_bounds__(256) void readout_kernel(const u16* __restrict__ nfb,
                                                      const float* __restrict__ y22p,
                                                      const float* __restrict__ Wr1,
                                                      const float* __restrict__ br1,
                                                      const float* __restrict__ Wr2,
                                                      const float* __restrict__ br2,
                                                      float* __restrict__ out) {
    const int b = blockIdx.x;
    const int t = threadIdx.x;
    __shared__ float y[128];
    __shared__ float hh[128];
    __shared__ float red[128];
    if (t < 92) {
        float s = 0.f;
        const u16* base = nfb + (size_t)b * 600 * 96 + t;
        for (int i = 0; i < 600; ++i) s += bf2f(base[(size_t)i * 96]);
        y[t] = s * (1.f / 600.f);
    } else if (t >= 128 && t < 164) {
        int f = t - 128;
        float s = 0.f;
        const float* base = y22p + (size_t)b * 1200 * 36 + f;
        for (int i = 0; i < 1200; ++i) s += base[(size_t)i * 36];
        y[92 + f] = s * (1.f / 1200.f);
    }
    __syncthreads();
    if (t < 128) {
        float s = br1[t];
        for (int c = 0; c < 128; ++c) s += y[c] * Wr1[(size_t)c * 128 + t];
        hh[t] = sigmoidf(s);
    }
    __syncthreads();
    if (t < 128) red[t] = hh[t] * Wr2[t];
    __syncthreads();
    for (int k = 64; k > 0; k >>= 1) {
        if (t < k) red[t] += red[t + k];
        __syncthreads();
    }
    if (t == 0) out[b] = sigmoidf(red[0] + br2[0]);
}

// ---------------- host side ----------------
static inline int cdiv(int a, int b) { return (a + b - 1) / b; }

extern "C" void kernel_launch(void* const* d_in, const int* in_sizes, int n_in,
                              void* d_out, int out_size, void* d_ws, size_t ws_size,
                              hipStream_t stream) {
    const int* gg_src = (const int*)d_in[0];
    const int* gg_dst = (const int*)d_in[1];
    const float* gg_nf = (const float*)d_in[2];
    const float* gg_ef = (const float*)d_in[3];
    const int* lg_src = (const int*)d_in[4];
    const int* lg_dst = (const int*)d_in[5];
    const float* lg_nf = (const float*)d_in[6];
    const float* lg_ef = (const float*)d_in[7];
    const float* W_node1 = (const float*)d_in[8];
    const float* b_node1 = (const float*)d_in[9];
    const float* W_ni1 = (const float*)d_in[10];
    const float* W_nj1 = (const float*)d_in[11];
    const float* W_fij1 = (const float*)d_in[12];
    const float* attn1 = (const float*)d_in[13];
    const float* bias1 = (const float*)d_in[14];
    const float* W_node2a = (const float*)d_in[15];
    const float* b_node2a = (const float*)d_in[16];
    const float* W_ni2a = (const float*)d_in[17];
    const float* W_nj2a = (const float*)d_in[18];
    const float* W_fij2a = (const float*)d_in[19];
    const float* attn2a = (const float*)d_in[20];
    const float* bias2a = (const float*)d_in[21];
    const float* W_node2b = (const float*)d_in[22];
    const float* b_node2b = (const float*)d_in[23];
    const float* W_ni2b = (const float*)d_in[24];
    const float* W_nj2b = (const float*)d_in[25];
    const float* W_fij2b = (const float*)d_in[26];
    const float* attn2b = (const float*)d_in[27];
    const float* bias2b = (const float*)d_in[28];
    const float* Wr1 = (const float*)d_in[29];
    const float* br1 = (const float*)d_in[30];
    const float* Wr2 = (const float*)d_in[31];
    const float* br2 = (const float*)d_in[32];
    float* out = (float*)d_out;

    char* ws = (char*)d_ws;
    size_t off = 0;
    auto take = [&](size_t bytes) {
        size_t o = off;
        off += (bytes + 255) & ~(size_t)255;
        return (void*)(ws + o);
    };
    float* y2n = (float*)take((size_t)NG * 40 * 4);
    float* y22p = (float*)take((size_t)NG * 36 * 4);
    float* esc = (float*)take((size_t)EG * 8 * 4);
    int* gg_row = (int*)take((size_t)(NG + 1) * 4);
    int* gg_eidx = (int*)take((size_t)EG * 4);
    int* gg_cnt = (int*)take((size_t)NG * 4);
    int* lg_row = (int*)take((size_t)(NL + 1) * 4);
    int* lg_eidx = (int*)take((size_t)EL * 4);
    int* lg_cnt = (int*)take((size_t)NL * 4);
    int* bsum = (int*)take((size_t)128 * 4);
    u16* gg_nf_bf = (u16*)take((size_t)NG * 64 * 2);
    u16* gg_ef_bf = (u16*)take((size_t)EG * 32 * 2);
    u16* lg_nf_bf = (u16*)take((size_t)NL * 96 * 2);
    u16* nfa_bf = (u16*)take((size_t)NL * 96 * 2);
    u16* nfb_bf = (u16*)take((size_t)NL * 96 * 2);
    u16* ef_shared = (u16*)take((size_t)EL * 64 * 2);   // ef2a input, then efa fsum
    u16* wt_ninj1 = (u16*)take((size_t)640 * 64 * 2);
    u16* wt_node1 = (u16*)take((size_t)320 * 64 * 2);
    u16* wt_fij1 = (u16*)take((size_t)320 * 32 * 2);
    u16* wt_ninj2a = (u16*)take((size_t)640 * 96 * 2);
    u16* wt_ninj2b = (u16*)take((size_t)640 * 96 * 2);
    u16* wt_fij2a = (u16*)take((size_t)320 * 64 * 2);
    u16* wt_fij2b = (u16*)take((size_t)320 * 64 * 2);
    u16* wt_node2a = (u16*)take((size_t)768 * 96 * 2);
    u16* wt_node2b = (u16*)take((size_t)768 * 96 * 2);
    float* attn_p1 = (float*)take((size_t)320 * 4);
    float* bias_cat1 = (float*)take((size_t)640 * 4);
    float* bias_cat2a = (float*)take((size_t)640 * 4);
    float* bias_cat2b = (float*)take((size_t)640 * 4);
    // slab: stage1 Pn1 [NG][640] + Pe chunk [EG/4][320]; stage2 Pn2 [NL][640] + Pe [EL][320]
    u16* slab = (u16*)take(((size_t)NG * 640 + (size_t)(EG / 4) * 320) * 2);  // 147.5 MB

    auto cvt = [&](const float* s, u16* d, int M, int K, int Kpad) {
        convert_pad_kernel<<<cdiv(M * Kpad, 256), 256, 0, stream>>>(s, d, M, K, Kpad);
    };
    auto wtr = [&](const float* W, int ldw, u16* d, int K, int N, int Nalloc, int Kpad) {
        wtrans_kernel<<<cdiv(Nalloc * Kpad, 256), 256, 0, stream>>>(W, ldw, d, K, N, Nalloc, Kpad);
    };
    auto build_csr = [&](const int* dst, int* row_ptr, int* eidx, int* cnt, int N, int E) {
        hipMemsetAsync(cnt, 0, (size_t)N * 4, stream);
        hist_kernel<<<cdiv(E, 256), 256, 0, stream>>>(dst, cnt, E);
        int nblk = cdiv(N, 1024);
        scan_block_kernel<<<nblk, 1024, 0, stream>>>(cnt, row_ptr, bsum, N);
        scan_top_kernel<<<1, 64, 0, stream>>>(bsum, nblk);
        scan_add_kernel<<<cdiv(N, 256), 256, 0, stream>>>(row_ptr, bsum, N, E);
        hipMemsetAsync(cnt, 0, (size_t)N * 4, stream);
        scatter_kernel<<<cdiv(E, 256), 256, 0, stream>>>(dst, row_ptr, cnt, eidx, E);
    };

    build_csr(gg_dst, gg_row, gg_eidx, gg_cnt, NG, EG);
    build_csr(lg_dst, lg_row, lg_eidx, lg_cnt, NL, EL);

    // prep: conversions + weight transforms + meta
    cvt(gg_nf, gg_nf_bf, NG, 40, 64);
    cvt(gg_ef, gg_ef_bf, EG, 10, 32);
    cvt(lg_nf, lg_nf_bf, NL, 92, 96);
    wtrans_hp_kernel<<<cdiv(320 * 64, 256), 256, 0, stream>>>(W_ni1, 288, wt_ninj1, 40, 64);
    wtrans_hp_kernel<<<cdiv(320 * 64, 256), 256, 0, stream>>>(W_nj1, 288, wt_ninj1 + 320 * 64, 40, 64);
    wtrans_hp_kernel<<<cdiv(320 * 32, 256), 256, 0, stream>>>(W_fij1, 288, wt_fij1, 10, 32);
    wtr(W_node1, 320, wt_node1, 40, 320, 320, 64);
    wtr(W_ni2a, 320, wt_ninj2a, 92, 320, 320, 96);
    wtr(W_nj2a, 320, wt_ninj2a + 320 * 96, 92, 320, 320, 96);
    wtr(W_ni2b, 320, wt_ninj2b, 92, 320, 320, 96);
    wtr(W_nj2b, 320, wt_ninj2b + 320 * 96, 92, 320, 320, 96);
    wtr(W_fij2a, 320, wt_fij2a, 40, 320, 320, 64);
    wtr(W_fij2b, 320, wt_fij2b, 40, 320, 320, 64);
    wtr(W_node2a, 736, wt_node2a, 92, 736, 768, 96);
    wtr(W_node2b, 736, wt_node2b, 92, 736, 768, 96);
    meta_kernel<<<cdiv(2240, 256), 256, 0, stream>>>(attn1, bias1, bias2a, bias2b,
                                                     attn_p1, bias_cat1, bias_cat2a, bias_cat2b);

    // ---------------- stage 1 (gg): single pass, 8 heads (FE padded 36->40) ----------------
    {
        u16* Pn1 = slab;                                  // [NG][640]
        u16* Pe1 = slab + (size_t)NG * 640;               // [EG/4][320] chunk
        gemm_bf_kernel<64><<<dim3(NG / 64, 10), 256, 0, stream>>>(
            gg_nf_bf, wt_ninj1, bias_cat1, Pn1, 640);
        for (int ch = 0; ch < 4; ++ch) {
            const int e0 = ch * (EG / 4);
            gemm_bf_kernel<32><<<dim3((EG / 4) / 64, 5), 256, 0, stream>>>(
                gg_ef_bf + (size_t)e0 * 32, wt_fij1, nullptr, Pe1, 320);
            edge_combine_kernel<1><<<(EG / 4) / 4, 256, 0, stream>>>(
                gg_src, gg_dst, Pn1, Pe1, attn_p1, esc, y22p, e0, EG / 4, NG);
        }
        csr_softmax_kernel<8><<<NG / 4, 256, 0, stream>>>(gg_row, gg_eidx, esc, NG);
        u16* Pnode1 = slab;   // alias: Pn1/Pe1 dead
        gemm_bf_kernel<64><<<dim3(NG / 64, 5), 256, 0, stream>>>(
            gg_nf_bf, wt_node1, b_node1, Pnode1, 320);
        node_agg_kernel<40, 8, 0><<<NG / 4, 256, 0, stream>>>(gg_row, gg_eidx, gg_src, esc,
                                                              Pnode1, y2n, NG);
    }

    // ef for lg layer 2a
    ef2a_kernel<<<cdiv(EL * 64, 256), 256, 0, stream>>>(lg_ef, y2n, ef_shared);

    // ---------------- stage 2 (lg), two layers ----------------
    for (int layer = 0; layer < 2; ++layer) {
        const bool a = (layer == 0);
        const u16* nf_in = a ? lg_nf_bf : nfa_bf;
        const u16* Wninj = a ? wt_ninj2a : wt_ninj2b;
        const u16* Wfij = a ? wt_fij2a : wt_fij2b;
        const u16* Wnode = a ? wt_node2a : wt_node2b;
        const float* bn = a ? b_node2a : b_node2b;
        const float* bcat = a ? bias_cat2a : bias_cat2b;
        const float* at = a ? attn2a : attn2b;
        u16* nf_out = a ? nfa_bf : nfb_bf;

        u16* Pn2 = slab;                                  // [NL][640]
        u16* Pe2 = slab + (size_t)NL * 640;               // [EL][320]
        gemm_bf_kernel<96><<<dim3(NL / 64, 10), 256, 0, stream>>>(nf_in, Wninj, bcat, Pn2, 640);
        gemm_bf_kernel<64><<<dim3(EL / 64, 5), 256, 0, stream>>>(ef_shared, Wfij, nullptr, Pe2, 320);
        if (a)
            edge_combine_kernel<2><<<EL / 4, 256, 0, stream>>>(
                lg_src, lg_dst, Pn2, Pe2, at, esc, ef_shared, 0, EL, EL);
        else
            edge_combine_kernel<0><<<EL / 4, 256, 0, stream>>>(
                lg_src, lg_dst, Pn2, Pe2, at, esc, nullptr, 0, EL, 0);
        csr_softmax_kernel<8><<<NL / 4, 256, 0, stream>>>(lg_row, lg_eidx, esc, NL);
        u16* Pnode2 = slab;   // alias: Pn2/Pe2 dead
        gemm_bf_kernel<96><<<dim3(NL / 64, 12), 256, 0, stream>>>(nf_in, Wnode, bn, Pnode2, 736);
        node_agg_kernel<92, 8, 1><<<NL / 4, 256, 0, stream>>>(lg_row, lg_eidx, lg_src, esc,
                                                              Pnode2, nf_out, NL);
    }

    // ---------------- readout ----------------
    readout_kernel<<<NB, 256, 0, stream>>>(nfb_bf, y22p, Wr1, br1, Wr2, br2, out);
}

// Round 10
// 1314.246 us; speedup vs baseline: 2.3832x; 1.0440x over previous
//
#include <hip/hip_runtime.h>
#include <math.h>

#define NG 76800
#define EG 307200
#define NL 38400
#define EL 153600
#define NB 64
#define NH 8

typedef __attribute__((ext_vector_type(8))) short bf16x8;
typedef __attribute__((ext_vector_type(4))) float f32x4;
typedef unsigned short u16;

__device__ __forceinline__ float sigmoidf(float x) { return 1.f / (1.f + expf(-x)); }
__device__ __forceinline__ u16 f2bf(float x) {
    unsigned u = __float_as_uint(x);
    return (u16)((u + 0x7FFFu + ((u >> 16) & 1u)) >> 16);
}
__device__ __forceinline__ float bf2f(u16 v) { return __uint_as_float(((unsigned)v) << 16); }

// ---------------- fp32 -> padded bf16 [M x Kpad] ----------------
__global__ __launch_bounds__(256) void convert_pad_kernel(const float* __restrict__ src,
                                                          u16* __restrict__ dst,
                                                          int M, int K, int Kpad) {
    int i = blockIdx.x * 256 + threadIdx.x;
    if (i >= M * Kpad) return;
    int m = i / Kpad, k = i - m * Kpad;
    dst[i] = (k < K) ? f2bf(src[(size_t)m * K + k]) : (u16)0;
}

// ---------------- W[K x Nfull] -> bf16 Wt[Nalloc x Kpad] (zero padded) ----------------
__global__ __launch_bounds__(256) void wtrans_kernel(const float* __restrict__ W, int ldw,
                                                     u16* __restrict__ dst,
                                                     int K, int N, int Nalloc, int Kpad) {
    int i = blockIdx.x * 256 + threadIdx.x;
    if (i >= Nalloc * Kpad) return;
    int n = i / Kpad, k = i - n * Kpad;
    dst[i] = (n < N && k < K) ? f2bf(W[(size_t)k * ldw + n]) : (u16)0;
}

// ---------------- head-padded transform: FE 36->40, 8 heads, R=320 rows ----------------
__global__ __launch_bounds__(256) void wtrans_hp_kernel(const float* __restrict__ W, int ldw,
                                                        u16* __restrict__ dst,
                                                        int K, int Kpad) {
    int i = blockIdx.x * 256 + threadIdx.x;
    if (i >= 320 * Kpad) return;
    int n = i / Kpad, k = i - n * Kpad;
    int hh = n / 40, f = n - hh * 40;
    float v = (k < K && f < 36) ? W[(size_t)k * ldw + hh * 36 + f] : 0.f;
    dst[i] = f2bf(v);
}

// ---------------- meta: padded attn1 + concat biases ----------------
__global__ __launch_bounds__(256) void meta_kernel(const float* __restrict__ attn1,
                                                   const float* __restrict__ bias1,
                                                   const float* __restrict__ b2a,
                                                   const float* __restrict__ b2b,
                                                   float* __restrict__ attn_p1,
                                                   float* __restrict__ bias_cat1,
                                                   float* __restrict__ bias_cat2a,
                                                   float* __restrict__ bias_cat2b) {
    int i = blockIdx.x * 256 + threadIdx.x;
    if (i < 320) {
        int hh = i / 40, f = i - hh * 40;
        attn_p1[i] = (f < 36) ? attn1[hh * 36 + f] : 0.f;
    } else if (i < 960) {
        int j = i - 320;
        float v = 0.f;
        if (j < 320) {
            int hh = j / 40, f = j - hh * 40;
            v = (f < 36) ? bias1[hh * 36 + f] : 0.f;
        }
        bias_cat1[j] = v;
    } else if (i < 1600) {
        int j = i - 960;
        bias_cat2a[j] = (j < 320) ? b2a[j] : 0.f;
    } else if (i < 2240) {
        int j = i - 1600;
        bias_cat2b[j] = (j < 320) ? b2b[j] : 0.f;
    }
}

// ---------------- LDS-free bf16 MFMA GEMM ----------------
template <int KPAD>
__global__ __launch_bounds__(256) void gemm_bf_kernel(const u16* __restrict__ A,
                                                      const u16* __restrict__ Wt,
                                                      const float* __restrict__ bias,
                                                      u16* __restrict__ C, int Ncols) {
    const int m0 = blockIdx.x * 64;
    const int n0 = blockIdx.y * 64;
    const int wv = threadIdx.x >> 6;
    const int lane = threadIdx.x & 63;
    const int q = lane >> 4;
    const int mr = lane & 15;

    const u16* Arow = A + (size_t)(m0 + wv * 16 + mr) * KPAD;
    f32x4 acc[4];
#pragma unroll
    for (int t = 0; t < 4; ++t) acc[t] = (f32x4){0.f, 0.f, 0.f, 0.f};

#pragma unroll
    for (int k0 = 0; k0 < KPAD; k0 += 32) {
        bf16x8 af = *(const bf16x8*)(Arow + k0 + q * 8);
#pragma unroll
        for (int t = 0; t < 4; ++t) {
            bf16x8 bv = *(const bf16x8*)(Wt + (size_t)(n0 + t * 16 + mr) * KPAD + k0 + q * 8);
            acc[t] = __builtin_amdgcn_mfma_f32_16x16x32_bf16(af, bv, acc[t], 0, 0, 0);
        }
    }

#pragma unroll
    for (int t = 0; t < 4; ++t) {
        int col = n0 + t * 16 + mr;
        if (col < Ncols) {
            float b = bias ? bias[col] : 0.f;
#pragma unroll
            for (int r = 0; r < 4; ++r) {
                int row = m0 + wv * 16 + q * 4 + r;
                C[(size_t)row * Ncols + col] = f2bf(acc[t][r] + b);
            }
        }
    }
}

// ---------------- ef2a = bf16(lg_ef + repeat(y2n,2)), padded to 64 ----------------
__global__ __launch_bounds__(256) void ef2a_kernel(const float* __restrict__ lg_ef,
                                                   const float* __restrict__ y2n,
                                                   u16* __restrict__ dst) {
    int i = blockIdx.x * 256 + threadIdx.x;
    if (i >= EL * 64) return;
    int e = i >> 6, c = i & 63;
    dst[i] = (c < 40) ? f2bf(lg_ef[(size_t)e * 40 + c] + y2n[(size_t)(e >> 1) * 40 + c]) : (u16)0;
}

// ---------------- edge combine: wave-per-edge, vectorized 16B loads ----------------
// FSMODE: 0 none; 1 fp32 out stride 36 (f<36, e<fsumE); 2 bf16 out stride 64 (e<fsumE).
template <int FSMODE>
__global__ __launch_bounds__(256) void edge_combine_kernel(
    const int* __restrict__ src, const int* __restrict__ dst,
    const u16* __restrict__ Pn, const u16* __restrict__ Pe,
    const float* __restrict__ attn,   // [320]
    float* __restrict__ esc,          // [E][8]
    void* __restrict__ fsum,
    int e0, int CH, int fsumE) {
    const int wid = threadIdx.x >> 6;
    const int lane = threadIdx.x & 63;
    const int idx = blockIdx.x * 4 + wid;
    if (idx >= CH) return;
    const int e = e0 + idx;
    const int lc = (lane < 40) ? lane : 39;
    const int h = lc / 5, o = lc - h * 5;
    const int c = h * 40 + o * 8;
    const bool act = (lane < 40);

    float attn_r[8];
#pragma unroll
    for (int j = 0; j < 8; ++j) attn_r[j] = attn[c + j];

    const int s = src[e], d = dst[e];
    bf16x8 api = *(const bf16x8*)(Pn + (size_t)s * 640 + c);
    bf16x8 apj = *(const bf16x8*)(Pn + (size_t)d * 640 + 320 + c);
    bf16x8 ape = *(const bf16x8*)(Pe + (size_t)idx * 320 + c);

    float v[8];
    float ehp = 0.f;
#pragma unroll
    for (int j = 0; j < 8; ++j) {
        float x = bf2f((u16)api[j]) + bf2f((u16)apj[j]) + bf2f((u16)ape[j]);
        x = x > 0.f ? x : 0.01f * x;   // leaky_relu(0.01)
        v[j] = x;
        ehp += x * attn_r[j];
    }
    float eh = 0.f;
#pragma unroll
    for (int k = 0; k < 5; ++k) eh += __shfl(ehp, h * 5 + k, 64);
    if (act && o == 0) esc[(size_t)e * 8 + h] = eh;

    if (FSMODE != 0 && e < fsumE) {
#pragma unroll
        for (int m = 4; m >= 1; m >>= 1) {
            const int p = (h ^ m) * 5 + o;
#pragma unroll
            for (int j = 0; j < 8; ++j) v[j] += __shfl(v[j], p, 64);
        }
        if (act && h == 0) {
#pragma unroll
            for (int j = 0; j < 8; ++j) {
                const int f = o * 8 + j;
                if (FSMODE == 1) {
                    if (f < 36) ((float*)fsum)[(size_t)e * 36 + f] = v[j];
                } else {
                    ((u16*)fsum)[(size_t)e * 64 + f] = f2bf(v[j]);
                }
            }
        }
    }
}

// ---------------- CSR build ----------------
__global__ __launch_bounds__(256) void hist_kernel(const int* __restrict__ dst,
                                                   int* __restrict__ cnt, int E) {
    int i = blockIdx.x * 256 + threadIdx.x;
    if (i < E) atomicAdd(&cnt[dst[i]], 1);
}

__global__ __launch_bounds__(1024) void scan_block_kernel(const int* __restrict__ cnt,
                                                          int* __restrict__ excl,
                                                          int* __restrict__ bsum, int N) {
    __shared__ int sd[1024];
    const int tid = threadIdx.x;
    const int i = blockIdx.x * 1024 + tid;
    int v = (i < N) ? cnt[i] : 0;
    sd[tid] = v;
    __syncthreads();
    for (int off = 1; off < 1024; off <<= 1) {
        int t = (tid >= off) ? sd[tid - off] : 0;
        __syncthreads();
        sd[tid] += t;
        __syncthreads();
    }
    if (i < N) excl[i] = sd[tid] - v;
    if (tid == 1023) bsum[blockIdx.x] = sd[1023];
}

__global__ void scan_top_kernel(int* __restrict__ bsum, int nblk) {
    if (threadIdx.x == 0 && blockIdx.x == 0) {
        int run = 0;
        for (int b = 0; b < nblk; ++b) {
            int t = bsum[b];
            bsum[b] = run;
            run += t;
        }
    }
}

__global__ __launch_bounds__(256) void scan_add_kernel(int* __restrict__ row_ptr,
                                                       const int* __restrict__ bsum,
                                                       int N, int E) {
    int i = blockIdx.x * 256 + threadIdx.x;
    if (i < N) row_ptr[i] += bsum[i >> 10];
    if (i == 0) row_ptr[N] = E;
}

// scatter: eidx (edge id, for softmax's esc gather) + srcs_csr (source node, for node_agg)
__global__ __launch_bounds__(256) void scatter_kernel(const int* __restrict__ dst,
                                                      const int* __restrict__ src,
                                                      const int* __restrict__ row_ptr,
                                                      int* __restrict__ cur,
                                                      int* __restrict__ eidx,
                                                      int* __restrict__ srcs, int E) {
    int i = blockIdx.x * 256 + threadIdx.x;
    if (i < E) {
        int d = dst[i];
        int pos = row_ptr[d] + atomicAdd(&cur[d], 1);
        eidx[pos] = i;
        srcs[pos] = src[i];
    }
}

// ---------------- CSR softmax: scores (edge order) -> weights in CSR order ----------------
template <int GH>
__global__ __launch_bounds__(256) void csr_softmax_kernel(
    const int* __restrict__ row_ptr, const int* __restrict__ eidx,
    const float* __restrict__ esc, float* __restrict__ wcsr, int N) {
    constexpr int NS = 64 / GH;
    const int wid = threadIdx.x >> 6;
    const int lane = threadIdx.x & 63;
    const int nid = blockIdx.x * 4 + wid;
    if (nid >= N) return;
    const int r0 = row_ptr[nid], r1 = row_ptr[nid + 1];
    const int h = lane & (GH - 1);
    const int slot = lane / GH;

    float mx = -1e30f;
    for (int i = r0 + slot; i < r1; i += NS)
        mx = fmaxf(mx, esc[(size_t)eidx[i] * GH + h]);
#pragma unroll
    for (int m = GH; m < 64; m <<= 1) mx = fmaxf(mx, __shfl_xor(mx, m, 64));

    float den = 0.f;
    for (int i = r0 + slot; i < r1; i += NS)
        den += expf(esc[(size_t)eidx[i] * GH + h] - mx);
#pragma unroll
    for (int m = GH; m < 64; m <<= 1) den += __shfl_xor(den, m, 64);
    const float rden = 1.f / den;

    for (int i = r0 + slot; i < r1; i += NS)
        wcsr[(size_t)i * GH + h] = expf(esc[(size_t)eidx[i] * GH + h] - mx) * rden;
}

// ---------------- node aggregation: sequential weights/srcs, single-gather ----------------
// OM 0: fp32 out stride Fn. OM 1: bf16 out stride 96 zero-padded 92..95.
template <int Fn, int GH, int OM>
__global__ __launch_bounds__(256) void node_agg_kernel(
    const int* __restrict__ row_ptr,
    const int* __restrict__ srcs,     // [E] CSR-ordered source node ids
    const float* __restrict__ wcsr,   // [E, GH] CSR-ordered softmax weights
    const u16* __restrict__ Pnode,    // [N, GH*Fn] bf16
    void* __restrict__ outp, int N) {
    constexpr int PAIRS = Fn / 2;     // Fn even: 20 / 46
    constexpr int STR = GH * Fn;
    const int wid = threadIdx.x >> 6;
    const int lane = threadIdx.x & 63;
    const int nid = blockIdx.x * 4 + wid;
    if (nid >= N) return;
    const int r0 = row_ptr[nid], r1 = row_ptr[nid + 1];
    const int col = 2 * lane;
    const bool act = (lane < PAIRS);

    float a0 = 0.f, a1 = 0.f;
#pragma unroll 2
    for (int i = r0; i < r1; ++i) {
        const int s = srcs[i];
        const float* wp = wcsr + (size_t)i * GH;
        const u16* pr = Pnode + (size_t)s * STR;
#pragma unroll
        for (int hh = 0; hh < GH; ++hh) {
            const float wt = wp[hh];
            if (act) {
                unsigned pv = *(const unsigned*)(pr + hh * Fn + col);
                a0 += wt * bf2f((u16)(pv & 0xFFFFu));
                a1 += wt * bf2f((u16)(pv >> 16));
            }
        }
    }
    if (OM == 0) {
        if (act) {
            float* op = (float*)outp + (size_t)nid * Fn + col;
            op[0] = a0;
            op[1] = a1;
        }
    } else {
        unsigned* ob = (unsigned*)((u16*)outp + (size_t)nid * 96);
        if (act) {
            unsigned pk = (unsigned)f2bf(a0) | ((unsigned)f2bf(a1) << 16);
            ob[lane] = pk;
        } else if (lane < 48) {
            ob[lane] = 0u;
        }
    }
}

// ---------------- readout ----------------
__global__ __launch_bounds__(256) void readout_kernel(const u16* __restrict__ nfb,
                                                      const float* __restrict__ y22p,
                                                      const float* __restrict__ Wr1,
                                                      const float* __restrict__ br1,
                                                      const float* __restrict__ Wr2,
                                                      const float* __restrict__ br2,
                                                      float* __restrict__ out) {
    const int b = blockIdx.x;
    const int t = threadIdx.x;
    __shared__ float y[128];
    __shared__ float hh[128];
    __shared__ float red[128];
    if (t < 92) {
        float s = 0.f;
        const u16* base = nfb + (size_t)b * 600 * 96 + t;
        for (int i = 0; i < 600; ++i) s += bf2f(base[(size_t)i * 96]);
        y[t] = s * (1.f / 600.f);
    } else if (t >= 128 && t < 164) {
        int f = t - 128;
        float s = 0.f;
        const float* base = y22p + (size_t)b * 1200 * 36 + f;
        for (int i = 0; i < 1200; ++i) s += base[(size_t)i * 36];
        y[92 + f] = s * (1.f / 1200.f);
    }
    __syncthreads();
    if (t < 128) {
        float s = br1[t];
        for (int c = 0; c < 128; ++c) s += y[c] * Wr1[(size_t)c * 128 + t];
        hh[t] = sigmoidf(s);
    }
    __syncthreads();
    if (t < 128) red[t] = hh[t] * Wr2[t];
    __syncthreads();
    for (int k = 64; k > 0; k >>= 1) {
        if (t < k) red[t] += red[t + k];
        __syncthreads();
    }
    if (t == 0) out[b] = sigmoidf(red[0] + br2[0]);
}

// ---------------- host side ----------------
static inline int cdiv(int a, int b) { return (a + b - 1) / b; }

extern "C" void kernel_launch(void* const* d_in, const int* in_sizes, int n_in,
                              void* d_out, int out_size, void* d_ws, size_t ws_size,
                              hipStream_t stream) {
    const int* gg_src = (const int*)d_in[0];
    const int* gg_dst = (const int*)d_in[1];
    const float* gg_nf = (const float*)d_in[2];
    const float* gg_ef = (const float*)d_in[3];
    const int* lg_src = (const int*)d_in[4];
    const int* lg_dst = (const int*)d_in[5];
    const float* lg_nf = (const float*)d_in[6];
    const float* lg_ef = (const float*)d_in[7];
    const float* W_node1 = (const float*)d_in[8];
    const float* b_node1 = (const float*)d_in[9];
    const float* W_ni1 = (const float*)d_in[10];
    const float* W_nj1 = (const float*)d_in[11];
    const float* W_fij1 = (const float*)d_in[12];
    const float* attn1 = (const float*)d_in[13];
    const float* bias1 = (const float*)d_in[14];
    const float* W_node2a = (const float*)d_in[15];
    const float* b_node2a = (const float*)d_in[16];
    const float* W_ni2a = (const float*)d_in[17];
    const float* W_nj2a = (const float*)d_in[18];
    const float* W_fij2a = (const float*)d_in[19];
    const float* attn2a = (const float*)d_in[20];
    const float* bias2a = (const float*)d_in[21];
    const float* W_node2b = (const float*)d_in[22];
    const float* b_node2b = (const float*)d_in[23];
    const float* W_ni2b = (const float*)d_in[24];
    const float* W_nj2b = (const float*)d_in[25];
    const float* W_fij2b = (const float*)d_in[26];
    const float* attn2b = (const float*)d_in[27];
    const float* bias2b = (const float*)d_in[28];
    const float* Wr1 = (const float*)d_in[29];
    const float* br1 = (const float*)d_in[30];
    const float* Wr2 = (const float*)d_in[31];
    const float* br2 = (const float*)d_in[32];
    float* out = (float*)d_out;

    char* ws = (char*)d_ws;
    size_t off = 0;
    auto take = [&](size_t bytes) {
        size_t o = off;
        off += (bytes + 255) & ~(size_t)255;
        return (void*)(ws + o);
    };
    float* y2n = (float*)take((size_t)NG * 40 * 4);
    float* y22p = (float*)take((size_t)NG * 36 * 4);
    float* esc = (float*)take((size_t)EG * 8 * 4);
    float* wcsr = (float*)take((size_t)EG * 8 * 4);
    int* gg_row = (int*)take((size_t)(NG + 1) * 4);
    int* gg_eidx = (int*)take((size_t)EG * 4);
    int* gg_srcs = (int*)take((size_t)EG * 4);
    int* gg_cnt = (int*)take((size_t)NG * 4);
    int* lg_row = (int*)take((size_t)(NL + 1) * 4);
    int* lg_eidx = (int*)take((size_t)EL * 4);
    int* lg_srcs = (int*)take((size_t)EL * 4);
    int* lg_cnt = (int*)take((size_t)NL * 4);
    int* bsum = (int*)take((size_t)128 * 4);
    u16* gg_nf_bf = (u16*)take((size_t)NG * 64 * 2);
    u16* gg_ef_bf = (u16*)take((size_t)EG * 32 * 2);
    u16* lg_nf_bf = (u16*)take((size_t)NL * 96 * 2);
    u16* nfa_bf = (u16*)take((size_t)NL * 96 * 2);
    u16* nfb_bf = (u16*)take((size_t)NL * 96 * 2);
    u16* ef_shared = (u16*)take((size_t)EL * 64 * 2);   // ef2a input, then efa fsum
    u16* wt_ninj1 = (u16*)take((size_t)640 * 64 * 2);
    u16* wt_node1 = (u16*)take((size_t)320 * 64 * 2);
    u16* wt_fij1 = (u16*)take((size_t)320 * 32 * 2);
    u16* wt_ninj2a = (u16*)take((size_t)640 * 96 * 2);
    u16* wt_ninj2b = (u16*)take((size_t)640 * 96 * 2);
    u16* wt_fij2a = (u16*)take((size_t)320 * 64 * 2);
    u16* wt_fij2b = (u16*)take((size_t)320 * 64 * 2);
    u16* wt_node2a = (u16*)take((size_t)768 * 96 * 2);
    u16* wt_node2b = (u16*)take((size_t)768 * 96 * 2);
    float* attn_p1 = (float*)take((size_t)320 * 4);
    float* bias_cat1 = (float*)take((size_t)640 * 4);
    float* bias_cat2a = (float*)take((size_t)640 * 4);
    float* bias_cat2b = (float*)take((size_t)640 * 4);
    u16* slab = (u16*)take(((size_t)NG * 640 + (size_t)(EG / 4) * 320) * 2);  // 147.5 MB

    auto cvt = [&](const float* s, u16* d, int M, int K, int Kpad) {
        convert_pad_kernel<<<cdiv(M * Kpad, 256), 256, 0, stream>>>(s, d, M, K, Kpad);
    };
    auto wtr = [&](const float* W, int ldw, u16* d, int K, int N, int Nalloc, int Kpad) {
        wtrans_kernel<<<cdiv(Nalloc * Kpad, 256), 256, 0, stream>>>(W, ldw, d, K, N, Nalloc, Kpad);
    };
    auto build_csr = [&](const int* dst, const int* src, int* row_ptr, int* eidx, int* srcs,
                         int* cnt, int N, int E) {
        hipMemsetAsync(cnt, 0, (size_t)N * 4, stream);
        hist_kernel<<<cdiv(E, 256), 256, 0, stream>>>(dst, cnt, E);
        int nblk = cdiv(N, 1024);
        scan_block_kernel<<<nblk, 1024, 0, stream>>>(cnt, row_ptr, bsum, N);
        scan_top_kernel<<<1, 64, 0, stream>>>(bsum, nblk);
        scan_add_kernel<<<cdiv(N, 256), 256, 0, stream>>>(row_ptr, bsum, N, E);
        hipMemsetAsync(cnt, 0, (size_t)N * 4, stream);
        scatter_kernel<<<cdiv(E, 256), 256, 0, stream>>>(dst, src, row_ptr, cnt, eidx, srcs, E);
    };

    build_csr(gg_dst, gg_src, gg_row, gg_eidx, gg_srcs, gg_cnt, NG, EG);
    build_csr(lg_dst, lg_src, lg_row, lg_eidx, lg_srcs, lg_cnt, NL, EL);

    // prep: conversions + weight transforms + meta
    cvt(gg_nf, gg_nf_bf, NG, 40, 64);
    cvt(gg_ef, gg_ef_bf, EG, 10, 32);
    cvt(lg_nf, lg_nf_bf, NL, 92, 96);
    wtrans_hp_kernel<<<cdiv(320 * 64, 256), 256, 0, stream>>>(W_ni1, 288, wt_ninj1, 40, 64);
    wtrans_hp_kernel<<<cdiv(320 * 64, 256), 256, 0, stream>>>(W_nj1, 288, wt_ninj1 + 320 * 64, 40, 64);
    wtrans_hp_kernel<<<cdiv(320 * 32, 256), 256, 0, stream>>>(W_fij1, 288, wt_fij1, 10, 32);
    wtr(W_node1, 320, wt_node1, 40, 320, 320, 64);
    wtr(W_ni2a, 320, wt_ninj2a, 92, 320, 320, 96);
    wtr(W_nj2a, 320, wt_ninj2a + 320 * 96, 92, 320, 320, 96);
    wtr(W_ni2b, 320, wt_ninj2b, 92, 320, 320, 96);
    wtr(W_nj2b, 320, wt_ninj2b + 320 * 96, 92, 320, 320, 96);
    wtr(W_fij2a, 320, wt_fij2a, 40, 320, 320, 64);
    wtr(W_fij2b, 320, wt_fij2b, 40, 320, 320, 64);
    wtr(W_node2a, 736, wt_node2a, 92, 736, 768, 96);
    wtr(W_node2b, 736, wt_node2b, 92, 736, 768, 96);
    meta_kernel<<<cdiv(2240, 256), 256, 0, stream>>>(attn1, bias1, bias2a, bias2b,
                                                     attn_p1, bias_cat1, bias_cat2a, bias_cat2b);

    // ---------------- stage 1 (gg): single pass, 8 heads (FE padded 36->40) ----------------
    {
        u16* Pn1 = slab;                                  // [NG][640]
        u16* Pe1 = slab + (size_t)NG * 640;               // [EG/4][320] chunk
        gemm_bf_kernel<64><<<dim3(NG / 64, 10), 256, 0, stream>>>(
            gg_nf_bf, wt_ninj1, bias_cat1, Pn1, 640);
        for (int ch = 0; ch < 4; ++ch) {
            const int e0 = ch * (EG / 4);
            gemm_bf_kernel<32><<<dim3((EG / 4) / 64, 5), 256, 0, stream>>>(
                gg_ef_bf + (size_t)e0 * 32, wt_fij1, nullptr, Pe1, 320);
            edge_combine_kernel<1><<<(EG / 4) / 4, 256, 0, stream>>>(
                gg_src, gg_dst, Pn1, Pe1, attn_p1, esc, y22p, e0, EG / 4, NG);
        }
        csr_softmax_kernel<8><<<NG / 4, 256, 0, stream>>>(gg_row, gg_eidx, esc, wcsr, NG);
        u16* Pnode1 = slab;   // alias: Pn1/Pe1 dead
        gemm_bf_kernel<64><<<dim3(NG / 64, 5), 256, 0, stream>>>(
            gg_nf_bf, wt_node1, b_node1, Pnode1, 320);
        node_agg_kernel<40, 8, 0><<<NG / 4, 256, 0, stream>>>(gg_row, gg_srcs, wcsr,
                                                              Pnode1, y2n, NG);
    }

    // ef for lg layer 2a
    ef2a_kernel<<<cdiv(EL * 64, 256), 256, 0, stream>>>(lg_ef, y2n, ef_shared);

    // ---------------- stage 2 (lg), two layers ----------------
    for (int layer = 0; layer < 2; ++layer) {
        const bool a = (layer == 0);
        const u16* nf_in = a ? lg_nf_bf : nfa_bf;
        const u16* Wninj = a ? wt_ninj2a : wt_ninj2b;
        const u16* Wfij = a ? wt_fij2a : wt_fij2b;
        const u16* Wnode = a ? wt_node2a : wt_node2b;
        const float* bn = a ? b_node2a : b_node2b;
        const float* bcat = a ? bias_cat2a : bias_cat2b;
        const float* at = a ? attn2a : attn2b;
        u16* nf_out = a ? nfa_bf : nfb_bf;

        u16* Pn2 = slab;                                  // [NL][640]
        u16* Pe2 = slab + (size_t)NL * 640;               // [EL][320]
        gemm_bf_kernel<96><<<dim3(NL / 64, 10), 256, 0, stream>>>(nf_in, Wninj, bcat, Pn2, 640);
        gemm_bf_kernel<64><<<dim3(EL / 64, 5), 256, 0, stream>>>(ef_shared, Wfij, nullptr, Pe2, 320);
        if (a)
            edge_combine_kernel<2><<<EL / 4, 256, 0, stream>>>(
                lg_src, lg_dst, Pn2, Pe2, at, esc, ef_shared, 0, EL, EL);
        else
            edge_combine_kernel<0><<<EL / 4, 256, 0, stream>>>(
                lg_src, lg_dst, Pn2, Pe2, at, esc, nullptr, 0, EL, 0);
        csr_softmax_kernel<8><<<NL / 4, 256, 0, stream>>>(lg_row, lg_eidx, esc, wcsr, NL);
        u16* Pnode2 = slab;   // alias: Pn2/Pe2 dead
        gemm_bf_kernel<96><<<dim3(NL / 64, 12), 256, 0, stream>>>(nf_in, Wnode, bn, Pnode2, 736);
        node_agg_kernel<92, 8, 1><<<NL / 4, 256, 0, stream>>>(lg_row, lg_srcs, wcsr,
                                                              Pnode2, nf_out, NL);
    }

    // ---------------- readout ----------------
    readout_kernel<<<NB, 256, 0, stream>>>(nfb_bf, y22p, Wr1, br1, Wr2, br2, out);
}

// Round 11
// 1129.046 us; speedup vs baseline: 2.7741x; 1.1640x over previous
//
#include <hip/hip_runtime.h>
#include <math.h>

#define NG 76800
#define EG 307200
#define NL 38400
#define EL 153600
#define NB 64
#define NH 8

typedef __attribute__((ext_vector_type(8))) short bf16x8;
typedef __attribute__((ext_vector_type(4))) float f32x4;
typedef unsigned short u16;

__device__ __forceinline__ float sigmoidf(float x) { return 1.f / (1.f + expf(-x)); }
__device__ __forceinline__ u16 f2bf(float x) {
    unsigned u = __float_as_uint(x);
    return (u16)((u + 0x7FFFu + ((u >> 16) & 1u)) >> 16);
}
__device__ __forceinline__ float bf2f(u16 v) { return __uint_as_float(((unsigned)v) << 16); }

// ---------------- fp32 -> padded bf16 [M x Kpad] ----------------
__global__ __launch_bounds__(256) void convert_pad_kernel(const float* __restrict__ src,
                                                          u16* __restrict__ dst,
                                                          int M, int K, int Kpad) {
    int i = blockIdx.x * 256 + threadIdx.x;
    if (i >= M * Kpad) return;
    int m = i / Kpad, k = i - m * Kpad;
    dst[i] = (k < K) ? f2bf(src[(size_t)m * K + k]) : (u16)0;
}

// ---------------- W[K x Nfull] -> bf16 Wt[Nalloc x Kpad] (zero padded) ----------------
__global__ __launch_bounds__(256) void wtrans_kernel(const float* __restrict__ W, int ldw,
                                                     u16* __restrict__ dst,
                                                     int K, int N, int Nalloc, int Kpad) {
    int i = blockIdx.x * 256 + threadIdx.x;
    if (i >= Nalloc * Kpad) return;
    int n = i / Kpad, k = i - n * Kpad;
    dst[i] = (n < N && k < K) ? f2bf(W[(size_t)k * ldw + n]) : (u16)0;
}

// ---------------- head-padded transform: FE 36->40, 8 heads, R=320 rows ----------------
__global__ __launch_bounds__(256) void wtrans_hp_kernel(const float* __restrict__ W, int ldw,
                                                        u16* __restrict__ dst,
                                                        int K, int Kpad) {
    int i = blockIdx.x * 256 + threadIdx.x;
    if (i >= 320 * Kpad) return;
    int n = i / Kpad, k = i - n * Kpad;
    int hh = n / 40, f = n - hh * 40;
    float v = (k < K && f < 36) ? W[(size_t)k * ldw + hh * 36 + f] : 0.f;
    dst[i] = f2bf(v);
}

// ---------------- meta: padded attn1 + concat biases ----------------
__global__ __launch_bounds__(256) void meta_kernel(const float* __restrict__ attn1,
                                                   const float* __restrict__ bias1,
                                                   const float* __restrict__ b2a,
                                                   const float* __restrict__ b2b,
                                                   float* __restrict__ attn_p1,
                                                   float* __restrict__ bias_cat1,
                                                   float* __restrict__ bias_cat2a,
                                                   float* __restrict__ bias_cat2b) {
    int i = blockIdx.x * 256 + threadIdx.x;
    if (i < 320) {
        int hh = i / 40, f = i - hh * 40;
        attn_p1[i] = (f < 36) ? attn1[hh * 36 + f] : 0.f;
    } else if (i < 960) {
        int j = i - 320;
        float v = 0.f;
        if (j < 320) {
            int hh = j / 40, f = j - hh * 40;
            v = (f < 36) ? bias1[hh * 36 + f] : 0.f;
        }
        bias_cat1[j] = v;
    } else if (i < 1600) {
        int j = i - 960;
        bias_cat2a[j] = (j < 320) ? b2a[j] : 0.f;
    } else if (i < 2240) {
        int j = i - 1600;
        bias_cat2b[j] = (j < 320) ? b2b[j] : 0.f;
    }
}

// ---------------- LDS-free bf16 MFMA GEMM ----------------
template <int KPAD>
__global__ __launch_bounds__(256) void gemm_bf_kernel(const u16* __restrict__ A,
                                                      const u16* __restrict__ Wt,
                                                      const float* __restrict__ bias,
                                                      u16* __restrict__ C, int Ncols) {
    const int m0 = blockIdx.x * 64;
    const int n0 = blockIdx.y * 64;
    const int wv = threadIdx.x >> 6;
    const int lane = threadIdx.x & 63;
    const int q = lane >> 4;
    const int mr = lane & 15;

    const u16* Arow = A + (size_t)(m0 + wv * 16 + mr) * KPAD;
    f32x4 acc[4];
#pragma unroll
    for (int t = 0; t < 4; ++t) acc[t] = (f32x4){0.f, 0.f, 0.f, 0.f};

#pragma unroll
    for (int k0 = 0; k0 < KPAD; k0 += 32) {
        bf16x8 af = *(const bf16x8*)(Arow + k0 + q * 8);
#pragma unroll
        for (int t = 0; t < 4; ++t) {
            bf16x8 bv = *(const bf16x8*)(Wt + (size_t)(n0 + t * 16 + mr) * KPAD + k0 + q * 8);
            acc[t] = __builtin_amdgcn_mfma_f32_16x16x32_bf16(af, bv, acc[t], 0, 0, 0);
        }
    }

#pragma unroll
    for (int t = 0; t < 4; ++t) {
        int col = n0 + t * 16 + mr;
        if (col < Ncols) {
            float b = bias ? bias[col] : 0.f;
#pragma unroll
            for (int r = 0; r < 4; ++r) {
                int row = m0 + wv * 16 + q * 4 + r;
                C[(size_t)row * Ncols + col] = f2bf(acc[t][r] + b);
            }
        }
    }
}

// ---------------- ef2a = bf16(lg_ef + repeat(y2n,2)), padded to 64 ----------------
__global__ __launch_bounds__(256) void ef2a_kernel(const float* __restrict__ lg_ef,
                                                   const float* __restrict__ y2n,
                                                   u16* __restrict__ dst) {
    int i = blockIdx.x * 256 + threadIdx.x;
    if (i >= EL * 64) return;
    int e = i >> 6, c = i & 63;
    dst[i] = (c < 40) ? f2bf(lg_ef[(size_t)e * 40 + c] + y2n[(size_t)(e >> 1) * 40 + c]) : (u16)0;
}

// ---------------- edge combine: wave-per-edge, vectorized 16B loads ----------------
// FSMODE: 0 none; 1 fp32 out stride 36 (f<36, e<fsumE); 2 bf16 out stride 64 (e<fsumE).
template <int FSMODE>
__global__ __launch_bounds__(256) void edge_combine_kernel(
    const int* __restrict__ src, const int* __restrict__ dst,
    const u16* __restrict__ Pn, const u16* __restrict__ Pe,
    const float* __restrict__ attn,   // [320]
    float* __restrict__ esc,          // [E][8]
    void* __restrict__ fsum,
    int e0, int CH, int fsumE) {
    const int wid = threadIdx.x >> 6;
    const int lane = threadIdx.x & 63;
    const int idx = blockIdx.x * 4 + wid;
    if (idx >= CH) return;
    const int e = e0 + idx;
    const int lc = (lane < 40) ? lane : 39;
    const int h = lc / 5, o = lc - h * 5;
    const int c = h * 40 + o * 8;
    const bool act = (lane < 40);

    float attn_r[8];
#pragma unroll
    for (int j = 0; j < 8; ++j) attn_r[j] = attn[c + j];

    const int s = src[e], d = dst[e];
    bf16x8 api = *(const bf16x8*)(Pn + (size_t)s * 640 + c);
    bf16x8 apj = *(const bf16x8*)(Pn + (size_t)d * 640 + 320 + c);
    bf16x8 ape = *(const bf16x8*)(Pe + (size_t)idx * 320 + c);

    float v[8];
    float ehp = 0.f;
#pragma unroll
    for (int j = 0; j < 8; ++j) {
        float x = bf2f((u16)api[j]) + bf2f((u16)apj[j]) + bf2f((u16)ape[j]);
        x = x > 0.f ? x : 0.01f * x;   // leaky_relu(0.01)
        v[j] = x;
        ehp += x * attn_r[j];
    }
    float eh = 0.f;
#pragma unroll
    for (int k = 0; k < 5; ++k) eh += __shfl(ehp, h * 5 + k, 64);
    if (act && o == 0) esc[(size_t)e * 8 + h] = eh;

    if (FSMODE != 0 && e < fsumE) {
#pragma unroll
        for (int m = 4; m >= 1; m >>= 1) {
            const int p = (h ^ m) * 5 + o;
#pragma unroll
            for (int j = 0; j < 8; ++j) v[j] += __shfl(v[j], p, 64);
        }
        if (act && h == 0) {
#pragma unroll
            for (int j = 0; j < 8; ++j) {
                const int f = o * 8 + j;
                if (FSMODE == 1) {
                    if (f < 36) ((float*)fsum)[(size_t)e * 36 + f] = v[j];
                } else {
                    ((u16*)fsum)[(size_t)e * 64 + f] = f2bf(v[j]);
                }
            }
        }
    }
}

// ---------------- CSR build ----------------
__global__ __launch_bounds__(256) void hist_kernel(const int* __restrict__ dst,
                                                   int* __restrict__ cnt, int E) {
    int i = blockIdx.x * 256 + threadIdx.x;
    if (i < E) atomicAdd(&cnt[dst[i]], 1);
}

__global__ __launch_bounds__(1024) void scan_block_kernel(const int* __restrict__ cnt,
                                                          int* __restrict__ excl,
                                                          int* __restrict__ bsum, int N) {
    __shared__ int sd[1024];
    const int tid = threadIdx.x;
    const int i = blockIdx.x * 1024 + tid;
    int v = (i < N) ? cnt[i] : 0;
    sd[tid] = v;
    __syncthreads();
    for (int off = 1; off < 1024; off <<= 1) {
        int t = (tid >= off) ? sd[tid - off] : 0;
        __syncthreads();
        sd[tid] += t;
        __syncthreads();
    }
    if (i < N) excl[i] = sd[tid] - v;
    if (tid == 1023) bsum[blockIdx.x] = sd[1023];
}

__global__ void scan_top_kernel(int* __restrict__ bsum, int nblk) {
    if (threadIdx.x == 0 && blockIdx.x == 0) {
        int run = 0;
        for (int b = 0; b < nblk; ++b) {
            int t = bsum[b];
            bsum[b] = run;
            run += t;
        }
    }
}

__global__ __launch_bounds__(256) void scan_add_kernel(int* __restrict__ row_ptr,
                                                       const int* __restrict__ bsum,
                                                       int N, int E) {
    int i = blockIdx.x * 256 + threadIdx.x;
    if (i < N) row_ptr[i] += bsum[i >> 10];
    if (i == 0) row_ptr[N] = E;
}

// scatter: eidx (edge id) + srcs_csr (source node ids, CSR order)
__global__ __launch_bounds__(256) void scatter_kernel(const int* __restrict__ dst,
                                                      const int* __restrict__ src,
                                                      const int* __restrict__ row_ptr,
                                                      int* __restrict__ cur,
                                                      int* __restrict__ eidx,
                                                      int* __restrict__ srcs, int E) {
    int i = blockIdx.x * 256 + threadIdx.x;
    if (i < E) {
        int d = dst[i];
        int pos = row_ptr[d] + atomicAdd(&cur[d], 1);
        eidx[pos] = i;
        srcs[pos] = src[i];
    }
}

// ---------------- CSR softmax: scores (edge order) -> weights in CSR order ----------------
template <int GH>
__global__ __launch_bounds__(256) void csr_softmax_kernel(
    const int* __restrict__ row_ptr, const int* __restrict__ eidx,
    const float* __restrict__ esc, float* __restrict__ wcsr, int N) {
    constexpr int NS = 64 / GH;
    const int wid = threadIdx.x >> 6;
    const int lane = threadIdx.x & 63;
    const int nid = blockIdx.x * 4 + wid;
    if (nid >= N) return;
    const int r0 = row_ptr[nid], r1 = row_ptr[nid + 1];
    const int h = lane & (GH - 1);
    const int slot = lane / GH;

    float mx = -1e30f;
    for (int i = r0 + slot; i < r1; i += NS)
        mx = fmaxf(mx, esc[(size_t)eidx[i] * GH + h]);
#pragma unroll
    for (int m = GH; m < 64; m <<= 1) mx = fmaxf(mx, __shfl_xor(mx, m, 64));

    float den = 0.f;
    for (int i = r0 + slot; i < r1; i += NS)
        den += expf(esc[(size_t)eidx[i] * GH + h] - mx);
#pragma unroll
    for (int m = GH; m < 64; m <<= 1) den += __shfl_xor(den, m, 64);
    const float rden = 1.f / den;

    for (int i = r0 + slot; i < r1; i += NS)
        wcsr[(size_t)i * GH + h] = expf(esc[(size_t)eidx[i] * GH + h] - mx) * rden;
}

// ---------------- node aggregation: 4-edge batched gathers for MLP ----------------
// OM 0: fp32 out stride Fn. OM 1: bf16 out stride 96 zero-padded 92..95.
// Per batch: resolve 4 src rows + 32 weights first, then issue ALL 32 gathered
// uint loads into registers, then FMA. Tail edges padded to last valid (w=0);
// deg >= 1 always (dst contains arange prefix), so r1-1 is valid.
template <int Fn, int GH, int OM>
__global__ __launch_bounds__(256) void node_agg_kernel(
    const int* __restrict__ row_ptr,
    const int* __restrict__ srcs,     // [E] CSR-ordered source node ids
    const float* __restrict__ wcsr,   // [E, GH] CSR-ordered softmax weights
    const u16* __restrict__ Pnode,    // [N, GH*Fn] bf16
    void* __restrict__ outp, int N) {
    constexpr int PAIRS = Fn / 2;     // Fn even: 20 / 46
    constexpr int STR = GH * Fn;
    const int wid = threadIdx.x >> 6;
    const int lane = threadIdx.x & 63;
    const int nid = blockIdx.x * 4 + wid;
    if (nid >= N) return;
    const int r0 = row_ptr[nid], r1 = row_ptr[nid + 1];
    const int col = 2 * lane;
    const bool act = (lane < PAIRS);

    float a0 = 0.f, a1 = 0.f;
    for (int i = r0; i < r1; i += 4) {
        const u16* prs[4];
        float wv[4][GH];
#pragma unroll
        for (int b = 0; b < 4; ++b) {
            const int ii = (i + b < r1) ? (i + b) : (r1 - 1);
            prs[b] = Pnode + (size_t)srcs[ii] * STR;
            const float live = (i + b < r1) ? 1.f : 0.f;
            const float* wp = wcsr + (size_t)ii * GH;
#pragma unroll
            for (int hh = 0; hh < GH; ++hh) wv[b][hh] = wp[hh] * live;
        }
        if (act) {
            unsigned pv[4][GH];
#pragma unroll
            for (int b = 0; b < 4; ++b)
#pragma unroll
                for (int hh = 0; hh < GH; ++hh)
                    pv[b][hh] = *(const unsigned*)(prs[b] + hh * Fn + col);
#pragma unroll
            for (int b = 0; b < 4; ++b)
#pragma unroll
                for (int hh = 0; hh < GH; ++hh) {
                    a0 += wv[b][hh] * bf2f((u16)(pv[b][hh] & 0xFFFFu));
                    a1 += wv[b][hh] * bf2f((u16)(pv[b][hh] >> 16));
                }
        }
    }
    if (OM == 0) {
        if (act) {
            float* op = (float*)outp + (size_t)nid * Fn + col;
            op[0] = a0;
            op[1] = a1;
        }
    } else {
        unsigned* ob = (unsigned*)((u16*)outp + (size_t)nid * 96);
        if (act) {
            unsigned pk = (unsigned)f2bf(a0) | ((unsigned)f2bf(a1) << 16);
            ob[lane] = pk;
        } else if (lane < 48) {
            ob[lane] = 0u;
        }
    }
}

// ---------------- readout ----------------
__global__ __launch_bounds__(256) void readout_kernel(const u16* __restrict__ nfb,
                                                      const float* __restrict__ y22p,
                                                      const float* __restrict__ Wr1,
                                                      const float* __restrict__ br1,
                                                      const float* __restrict__ Wr2,
                                                      const float* __restrict__ br2,
                                                      float* __restrict__ out) {
    const int b = blockIdx.x;
    const int t = threadIdx.x;
    __shared__ float y[128];
    __shared__ float hh[128];
    __shared__ float red[128];
    if (t < 92) {
        float s = 0.f;
        const u16* base = nfb + (size_t)b * 600 * 96 + t;
        for (int i = 0; i < 600; ++i) s += bf2f(base[(size_t)i * 96]);
        y[t] = s * (1.f / 600.f);
    } else if (t >= 128 && t < 164) {
        int f = t - 128;
        float s = 0.f;
        const float* base = y22p + (size_t)b * 1200 * 36 + f;
        for (int i = 0; i < 1200; ++i) s += base[(size_t)i * 36];
        y[92 + f] = s * (1.f / 1200.f);
    }
    __syncthreads();
    if (t < 128) {
        float s = br1[t];
        for (int c = 0; c < 128; ++c) s += y[c] * Wr1[(size_t)c * 128 + t];
        hh[t] = sigmoidf(s);
    }
    __syncthreads();
    if (t < 128) red[t] = hh[t] * Wr2[t];
    __syncthreads();
    for (int k = 64; k > 0; k >>= 1) {
        if (t < k) red[t] += red[t + k];
        __syncthreads();
    }
    if (t == 0) out[b] = sigmoidf(red[0] + br2[0]);
}

// ---------------- host side ----------------
static inline int cdiv(int a, int b) { return (a + b - 1) / b; }

extern "C" void kernel_launch(void* const* d_in, const int* in_sizes, int n_in,
                              void* d_out, int out_size, void* d_ws, size_t ws_size,
                              hipStream_t stream) {
    const int* gg_src = (const int*)d_in[0];
    const int* gg_dst = (const int*)d_in[1];
    const float* gg_nf = (const float*)d_in[2];
    const float* gg_ef = (const float*)d_in[3];
    const int* lg_src = (const int*)d_in[4];
    const int* lg_dst = (const int*)d_in[5];
    const float* lg_nf = (const float*)d_in[6];
    const float* lg_ef = (const float*)d_in[7];
    const float* W_node1 = (const float*)d_in[8];
    const float* b_node1 = (const float*)d_in[9];
    const float* W_ni1 = (const float*)d_in[10];
    const float* W_nj1 = (const float*)d_in[11];
    const float* W_fij1 = (const float*)d_in[12];
    const float* attn1 = (const float*)d_in[13];
    const float* bias1 = (const float*)d_in[14];
    const float* W_node2a = (const float*)d_in[15];
    const float* b_node2a = (const float*)d_in[16];
    const float* W_ni2a = (const float*)d_in[17];
    const float* W_nj2a = (const float*)d_in[18];
    const float* W_fij2a = (const float*)d_in[19];
    const float* attn2a = (const float*)d_in[20];
    const float* bias2a = (const float*)d_in[21];
    const float* W_node2b = (const float*)d_in[22];
    const float* b_node2b = (const float*)d_in[23];
    const float* W_ni2b = (const float*)d_in[24];
    const float* W_nj2b = (const float*)d_in[25];
    const float* W_fij2b = (const float*)d_in[26];
    const float* attn2b = (const float*)d_in[27];
    const float* bias2b = (const float*)d_in[28];
    const float* Wr1 = (const float*)d_in[29];
    const float* br1 = (const float*)d_in[30];
    const float* Wr2 = (const float*)d_in[31];
    const float* br2 = (const float*)d_in[32];
    float* out = (float*)d_out;

    char* ws = (char*)d_ws;
    size_t off = 0;
    auto take = [&](size_t bytes) {
        size_t o = off;
        off += (bytes + 255) & ~(size_t)255;
        return (void*)(ws + o);
    };
    float* y2n = (float*)take((size_t)NG * 40 * 4);
    float* y22p = (float*)take((size_t)NG * 36 * 4);
    float* esc = (float*)take((size_t)EG * 8 * 4);
    float* wcsr = (float*)take((size_t)EG * 8 * 4);
    int* gg_row = (int*)take((size_t)(NG + 1) * 4);
    int* gg_eidx = (int*)take((size_t)EG * 4);
    int* gg_srcs = (int*)take((size_t)EG * 4);
    int* gg_cnt = (int*)take((size_t)NG * 4);
    int* lg_row = (int*)take((size_t)(NL + 1) * 4);
    int* lg_eidx = (int*)take((size_t)EL * 4);
    int* lg_srcs = (int*)take((size_t)EL * 4);
    int* lg_cnt = (int*)take((size_t)NL * 4);
    int* bsum = (int*)take((size_t)128 * 4);
    u16* gg_nf_bf = (u16*)take((size_t)NG * 64 * 2);
    u16* gg_ef_bf = (u16*)take((size_t)EG * 32 * 2);
    u16* lg_nf_bf = (u16*)take((size_t)NL * 96 * 2);
    u16* nfa_bf = (u16*)take((size_t)NL * 96 * 2);
    u16* nfb_bf = (u16*)take((size_t)NL * 96 * 2);
    u16* ef_shared = (u16*)take((size_t)EL * 64 * 2);   // ef2a input, then efa fsum
    u16* wt_ninj1 = (u16*)take((size_t)640 * 64 * 2);
    u16* wt_node1 = (u16*)take((size_t)320 * 64 * 2);
    u16* wt_fij1 = (u16*)take((size_t)320 * 32 * 2);
    u16* wt_ninj2a = (u16*)take((size_t)640 * 96 * 2);
    u16* wt_ninj2b = (u16*)take((size_t)640 * 96 * 2);
    u16* wt_fij2a = (u16*)take((size_t)320 * 64 * 2);
    u16* wt_fij2b = (u16*)take((size_t)320 * 64 * 2);
    u16* wt_node2a = (u16*)take((size_t)768 * 96 * 2);
    u16* wt_node2b = (u16*)take((size_t)768 * 96 * 2);
    float* attn_p1 = (float*)take((size_t)320 * 4);
    float* bias_cat1 = (float*)take((size_t)640 * 4);
    float* bias_cat2a = (float*)take((size_t)640 * 4);
    float* bias_cat2b = (float*)take((size_t)640 * 4);
    u16* slab = (u16*)take(((size_t)NG * 640 + (size_t)(EG / 4) * 320) * 2);  // 147.5 MB

    auto cvt = [&](const float* s, u16* d, int M, int K, int Kpad) {
        convert_pad_kernel<<<cdiv(M * Kpad, 256), 256, 0, stream>>>(s, d, M, K, Kpad);
    };
    auto wtr = [&](const float* W, int ldw, u16* d, int K, int N, int Nalloc, int Kpad) {
        wtrans_kernel<<<cdiv(Nalloc * Kpad, 256), 256, 0, stream>>>(W, ldw, d, K, N, Nalloc, Kpad);
    };
    auto build_csr = [&](const int* dst, const int* src, int* row_ptr, int* eidx, int* srcs,
                         int* cnt, int N, int E) {
        hipMemsetAsync(cnt, 0, (size_t)N * 4, stream);
        hist_kernel<<<cdiv(E, 256), 256, 0, stream>>>(dst, cnt, E);
        int nblk = cdiv(N, 1024);
        scan_block_kernel<<<nblk, 1024, 0, stream>>>(cnt, row_ptr, bsum, N);
        scan_top_kernel<<<1, 64, 0, stream>>>(bsum, nblk);
        scan_add_kernel<<<cdiv(N, 256), 256, 0, stream>>>(row_ptr, bsum, N, E);
        hipMemsetAsync(cnt, 0, (size_t)N * 4, stream);
        scatter_kernel<<<cdiv(E, 256), 256, 0, stream>>>(dst, src, row_ptr, cnt, eidx, srcs, E);
    };

    build_csr(gg_dst, gg_src, gg_row, gg_eidx, gg_srcs, gg_cnt, NG, EG);
    build_csr(lg_dst, lg_src, lg_row, lg_eidx, lg_srcs, lg_cnt, NL, EL);

    // prep: conversions + weight transforms + meta
    cvt(gg_nf, gg_nf_bf, NG, 40, 64);
    cvt(gg_ef, gg_ef_bf, EG, 10, 32);
    cvt(lg_nf, lg_nf_bf, NL, 92, 96);
    wtrans_hp_kernel<<<cdiv(320 * 64, 256), 256, 0, stream>>>(W_ni1, 288, wt_ninj1, 40, 64);
    wtrans_hp_kernel<<<cdiv(320 * 64, 256), 256, 0, stream>>>(W_nj1, 288, wt_ninj1 + 320 * 64, 40, 64);
    wtrans_hp_kernel<<<cdiv(320 * 32, 256), 256, 0, stream>>>(W_fij1, 288, wt_fij1, 10, 32);
    wtr(W_node1, 320, wt_node1, 40, 320, 320, 64);
    wtr(W_ni2a, 320, wt_ninj2a, 92, 320, 320, 96);
    wtr(W_nj2a, 320, wt_ninj2a + 320 * 96, 92, 320, 320, 96);
    wtr(W_ni2b, 320, wt_ninj2b, 92, 320, 320, 96);
    wtr(W_nj2b, 320, wt_ninj2b + 320 * 96, 92, 320, 320, 96);
    wtr(W_fij2a, 320, wt_fij2a, 40, 320, 320, 64);
    wtr(W_fij2b, 320, wt_fij2b, 40, 320, 320, 64);
    wtr(W_node2a, 736, wt_node2a, 92, 736, 768, 96);
    wtr(W_node2b, 736, wt_node2b, 92, 736, 768, 96);
    meta_kernel<<<cdiv(2240, 256), 256, 0, stream>>>(attn1, bias1, bias2a, bias2b,
                                                     attn_p1, bias_cat1, bias_cat2a, bias_cat2b);

    // ---------------- stage 1 (gg): single pass, 8 heads (FE padded 36->40) ----------------
    {
        u16* Pn1 = slab;                                  // [NG][640]
        u16* Pe1 = slab + (size_t)NG * 640;               // [EG/4][320] chunk
        gemm_bf_kernel<64><<<dim3(NG / 64, 10), 256, 0, stream>>>(
            gg_nf_bf, wt_ninj1, bias_cat1, Pn1, 640);
        for (int ch = 0; ch < 4; ++ch) {
            const int e0 = ch * (EG / 4);
            gemm_bf_kernel<32><<<dim3((EG / 4) / 64, 5), 256, 0, stream>>>(
                gg_ef_bf + (size_t)e0 * 32, wt_fij1, nullptr, Pe1, 320);
            edge_combine_kernel<1><<<(EG / 4) / 4, 256, 0, stream>>>(
                gg_src, gg_dst, Pn1, Pe1, attn_p1, esc, y22p, e0, EG / 4, NG);
        }
        csr_softmax_kernel<8><<<NG / 4, 256, 0, stream>>>(gg_row, gg_eidx, esc, wcsr, NG);
        u16* Pnode1 = slab;   // alias: Pn1/Pe1 dead
        gemm_bf_kernel<64><<<dim3(NG / 64, 5), 256, 0, stream>>>(
            gg_nf_bf, wt_node1, b_node1, Pnode1, 320);
        node_agg_kernel<40, 8, 0><<<NG / 4, 256, 0, stream>>>(gg_row, gg_srcs, wcsr,
                                                              Pnode1, y2n, NG);
    }

    // ef for lg layer 2a
    ef2a_kernel<<<cdiv(EL * 64, 256), 256, 0, stream>>>(lg_ef, y2n, ef_shared);

    // ---------------- stage 2 (lg), two layers ----------------
    for (int layer = 0; layer < 2; ++layer) {
        const bool a = (layer == 0);
        const u16* nf_in = a ? lg_nf_bf : nfa_bf;
        const u16* Wninj = a ? wt_ninj2a : wt_ninj2b;
        const u16* Wfij = a ? wt_fij2a : wt_fij2b;
        const u16* Wnode = a ? wt_node2a : wt_node2b;
        const float* bn = a ? b_node2a : b_node2b;
        const float* bcat = a ? bias_cat2a : bias_cat2b;
        const float* at = a ? attn2a : attn2b;
        u16* nf_out = a ? nfa_bf : nfb_bf;

        u16* Pn2 = slab;                                  // [NL][640]
        u16* Pe2 = slab + (size_t)NL * 640;               // [EL][320]
        gemm_bf_kernel<96><<<dim3(NL / 64, 10), 256, 0, stream>>>(nf_in, Wninj, bcat, Pn2, 640);
        gemm_bf_kernel<64><<<dim3(EL / 64, 5), 256, 0, stream>>>(ef_shared, Wfij, nullptr, Pe2, 320);
        if (a)
            edge_combine_kernel<2><<<EL / 4, 256, 0, stream>>>(
                lg_src, lg_dst, Pn2, Pe2, at, esc, ef_shared, 0, EL, EL);
        else
            edge_combine_kernel<0><<<EL / 4, 256, 0, stream>>>(
                lg_src, lg_dst, Pn2, Pe2, at, esc, nullptr, 0, EL, 0);
        csr_softmax_kernel<8><<<NL / 4, 256, 0, stream>>>(lg_row, lg_eidx, esc, wcsr, NL);
        u16* Pnode2 = slab;   // alias: Pn2/Pe2 dead
        gemm_bf_kernel<96><<<dim3(NL / 64, 12), 256, 0, stream>>>(nf_in, Wnode, bn, Pnode2, 736);
        node_agg_kernel<92, 8, 1><<<NL / 4, 256, 0, stream>>>(lg_row, lg_srcs, wcsr,
                                                              Pnode2, nf_out, NL);
    }

    // ---------------- readout ----------------
    readout_kernel<<<NB, 256, 0, stream>>>(nfb_bf, y22p, Wr1, br1, Wr2, br2, out);
}